// Round 1
// baseline (1234.254 us; speedup 1.0000x reference)
//
#include <hip/hip_runtime.h>

#define NG 64
#define HIDW 200
#define DIN 128

// ---------------- degree / CSR build ----------------

__global__ void count_kernel(const int* __restrict__ dst, int* __restrict__ counts, int E) {
  int e = blockIdx.x * 256 + threadIdx.x;
  if (e < E) atomicAdd(&counts[dst[e]], 1);
}

__global__ void dinv_kernel(const int* __restrict__ counts, float* __restrict__ dinv, int n) {
  int i = blockIdx.x * 256 + threadIdx.x;
  if (i < n) dinv[i] = rsqrtf((float)(counts[i] + 1));  // +1 self-loop, always >=1
}

__global__ __launch_bounds__(1024) void scan_kernel(const int* __restrict__ counts,
                                                    int* __restrict__ row_ptr, int n) {
  __shared__ int ssum[1024];
  int tid = threadIdx.x;
  int per = (n + 1023) / 1024;
  int start = tid * per;
  int end = start + per; if (end > n) end = n;
  int s = 0;
  for (int i = start; i < end; ++i) s += counts[i];
  ssum[tid] = s;
  __syncthreads();
  for (int off = 1; off < 1024; off <<= 1) {
    int v = 0;
    if (tid >= off) v = ssum[tid - off];
    __syncthreads();
    if (tid >= off) ssum[tid] += v;
    __syncthreads();
  }
  int run = ssum[tid] - s;  // exclusive prefix of this thread's chunk
  for (int i = start; i < end; ++i) { row_ptr[i] = run; run += counts[i]; }
  if (tid == 1023) row_ptr[n] = ssum[1023];
}

__global__ void fill_kernel(const int* __restrict__ src, const int* __restrict__ dst,
                            const int* __restrict__ row_ptr, int* __restrict__ fill,
                            const float* __restrict__ dinv,
                            int* __restrict__ csr_src, float* __restrict__ csr_w, int E) {
  int e = blockIdx.x * 256 + threadIdx.x;
  if (e >= E) return;
  int d = dst[e];
  int pos = row_ptr[d] + atomicAdd(&fill[d], 1);
  int s = src[e];
  csr_src[pos] = s;
  csr_w[pos] = dinv[s];
}

__global__ void gstart_kernel(const int* __restrict__ batch, int* __restrict__ gs, int n) {
  int i = blockIdx.x * 256 + threadIdx.x;
  if (i >= n) return;
  int b = batch[i];
  if (i == 0) {
    for (int g = 0; g <= b; ++g) gs[g] = 0;
  } else {
    int bp = batch[i - 1];
    for (int g = bp + 1; g <= b; ++g) gs[g] = i;
  }
  if (i == n - 1) {
    for (int g = b + 1; g <= NG; ++g) gs[g] = n;
  }
}

// ---------------- aggregation: out = D^-1/2 (Adj+I) D^-1/2 h ----------------
// one wave per node; lane handles a float4 feature chunk

template <int D>
__global__ __launch_bounds__(256) void agg_kernel(const float* __restrict__ h,
                                                  const int* __restrict__ row_ptr,
                                                  const int* __restrict__ csr_src,
                                                  const float* __restrict__ csr_w,
                                                  const float* __restrict__ dinv,
                                                  float* __restrict__ out, int n) {
  constexpr int C = D / 4;
  int node = blockIdx.x * 4 + (threadIdx.x >> 6);
  int lane = threadIdx.x & 63;
  if (node >= n || lane >= C) return;
  const float4* hp = (const float4*)h;
  float di = dinv[node];
  int e0 = row_ptr[node], e1 = row_ptr[node + 1];
  float4 self = hp[(long)node * C + lane];
  float ax = di * self.x, ay = di * self.y, az = di * self.z, aw = di * self.w;
  for (int e = e0; e < e1; ++e) {
    int s = csr_src[e];
    float w = csr_w[e];
    float4 v = hp[(long)s * C + lane];
    ax = fmaf(w, v.x, ax);
    ay = fmaf(w, v.y, ay);
    az = fmaf(w, v.z, az);
    aw = fmaf(w, v.w, aw);
  }
  float4 r; r.x = di * ax; r.y = di * ay; r.z = di * az; r.w = di * aw;
  ((float4*)out)[(long)node * C + lane] = r;
}

// ---------------- fp32 GEMM: out[N][200] = A[N][K] @ W[K][200] + b (opt relu) ---------
// BM=64, BN=128 (grid.y=2 covers 200 cols), Kt=32, thread tile 4x8, 256 threads

template <int K, bool RELU>
__global__ __launch_bounds__(256) void gemm_kernel(const float* __restrict__ A,
                                                   const float* __restrict__ W,
                                                   const float* __restrict__ bias,
                                                   float* __restrict__ out, int N) {
  const int M = HIDW;
  __shared__ float As[64][33];   // pad 33: conflict-free scalar reads
  __shared__ float Bs[32][128];
  int row0 = blockIdx.x * 64;
  int col0 = blockIdx.y * 128;
  int tid = threadIdx.x;
  int tx = tid & 15;   // col group (8 cols each)
  int ty = tid >> 4;   // row group (4 rows each)
  float acc[4][8] = {{0.f}};

  for (int k0 = 0; k0 < K; k0 += 32) {
#pragma unroll
    for (int i = 0; i < 8; ++i) {  // stage A: 64x32
      int idx = tid + i * 256;
      int r = idx >> 5, c = idx & 31;
      int k = k0 + c;
      As[r][c] = (k < K) ? A[(long)(row0 + r) * K + k] : 0.f;
    }
#pragma unroll
    for (int i = 0; i < 16; ++i) {  // stage B: 32x128
      int idx = tid + i * 256;
      int r = idx >> 7, c = idx & 127;
      int k = k0 + r, col = col0 + c;
      Bs[r][c] = (k < K && col < M) ? W[(long)k * M + col] : 0.f;
    }
    __syncthreads();
#pragma unroll
    for (int k = 0; k < 32; ++k) {
      float4 b0 = *(const float4*)&Bs[k][tx * 8];
      float4 b1 = *(const float4*)&Bs[k][tx * 8 + 4];
      float bb[8] = {b0.x, b0.y, b0.z, b0.w, b1.x, b1.y, b1.z, b1.w};
#pragma unroll
      for (int i = 0; i < 4; ++i) {
        float av = As[ty * 4 + i][k];
#pragma unroll
        for (int j = 0; j < 8; ++j) acc[i][j] = fmaf(av, bb[j], acc[i][j]);
      }
    }
    __syncthreads();
  }

#pragma unroll
  for (int i = 0; i < 4; ++i) {
    int row = row0 + ty * 4 + i;
#pragma unroll
    for (int j = 0; j < 8; ++j) {
      int col = col0 + tx * 8 + j;
      if (col < M) {
        float v = acc[i][j] + bias[col];
        if (RELU) v = fmaxf(v, 0.f);
        out[(long)row * M + col] = v;
      }
    }
  }
}

// ---------------- gated mean pool: pooled[g] = mean(h3 * sigmoid(gate)) ----------------

__global__ void pool_kernel(const float* __restrict__ h3, const float* __restrict__ gate,
                            const int* __restrict__ gs, float* __restrict__ pooled) {
  int g = blockIdx.x;
  int f = blockIdx.y * 64 + threadIdx.x;
  if (f >= HIDW) return;
  int s = gs[g], e = gs[g + 1];
  float acc = 0.f;
  for (int i = s; i < e; ++i) {
    float v = h3[(long)i * HIDW + f];
    float gt = gate[(long)i * HIDW + f];
    acc += v * (1.f / (1.f + __expf(-gt)));
  }
  float cnt = fmaxf((float)(e - s), 1.f);
  pooled[g * HIDW + f] = acc / cnt;
}

// ---------------- classifier: relu(pooled@Wc1+bc1)@Wc2+bc2 ----------------

__global__ void classifier_kernel(const float* __restrict__ pooled,
                                  const float* __restrict__ Wc1, const float* __restrict__ bc1,
                                  const float* __restrict__ Wc2, const float* __restrict__ bc2,
                                  float* __restrict__ out) {
  int g = blockIdx.x;
  int tid = threadIdx.x;
  __shared__ float pg[HIDW];
  __shared__ float hid[100];
  if (tid < HIDW) pg[tid] = pooled[g * HIDW + tid];
  __syncthreads();
  if (tid < 100) {
    float a = bc1[tid];
    for (int k = 0; k < HIDW; ++k) a = fmaf(pg[k], Wc1[k * 100 + tid], a);
    hid[tid] = fmaxf(a, 0.f);
  }
  __syncthreads();
  if (tid < 2) {
    float a = bc2[tid];
    for (int k = 0; k < 100; ++k) a = fmaf(hid[k], Wc2[k * 2 + tid], a);
    out[g * 2 + tid] = a;
  }
}

// ---------------- launch ----------------

extern "C" void kernel_launch(void* const* d_in, const int* in_sizes, int n_in,
                              void* d_out, int out_size, void* d_ws, size_t ws_size,
                              hipStream_t stream) {
  const float* x    = (const float*)d_in[0];
  const int*   ei   = (const int*)d_in[1];
  const int*   batch= (const int*)d_in[2];
  const float* W1 = (const float*)d_in[3];  const float* b1 = (const float*)d_in[4];
  const float* W2 = (const float*)d_in[5];  const float* b2 = (const float*)d_in[6];
  const float* W3 = (const float*)d_in[7];  const float* b3 = (const float*)d_in[8];
  const float* Wg = (const float*)d_in[9];  const float* bg = (const float*)d_in[10];
  const float* Wc1= (const float*)d_in[11]; const float* bc1= (const float*)d_in[12];
  const float* Wc2= (const float*)d_in[13]; const float* bc2= (const float*)d_in[14];
  float* out = (float*)d_out;

  const int n = in_sizes[0] / DIN;     // 40000
  const int E = in_sizes[1] / 2;       // 640000
  const int* src = ei;
  const int* dst = ei + E;

  // workspace carve-up (all offsets multiple of 4 elements -> float4-safe)
  int* counts   = (int*)d_ws;               // n
  int* fill     = counts + n;               // n
  int* row_ptr  = fill + n;                 // n+1 (pad to n+4)
  int* gs       = row_ptr + (n + 4);        // 65 (pad to 68)
  float* dinv   = (float*)(gs + 68);        // n
  int* csr_src  = (int*)(dinv + n);         // E
  float* csr_w  = (float*)(csr_src + E);    // E
  float* pooled = csr_w + E;                // 64*200
  float* bufA   = pooled + NG * HIDW;       // n*200
  float* bufB   = bufA + (long)n * HIDW;    // n*200

  hipMemsetAsync(counts, 0, (size_t)2 * n * sizeof(int), stream);  // counts + fill

  int eb = (E + 255) / 256;
  int nb = (n + 255) / 256;
  count_kernel<<<eb, 256, 0, stream>>>(dst, counts, E);
  dinv_kernel<<<nb, 256, 0, stream>>>(counts, dinv, n);
  scan_kernel<<<1, 1024, 0, stream>>>(counts, row_ptr, n);
  fill_kernel<<<eb, 256, 0, stream>>>(src, dst, row_ptr, fill, dinv, csr_src, csr_w, E);
  gstart_kernel<<<nb, 256, 0, stream>>>(batch, gs, n);

  int ab = (n + 3) / 4;
  dim3 ggrid(n / 64, 2);

  // layer 1: agg(x) [D=128] -> gemm K=128
  agg_kernel<DIN><<<ab, 256, 0, stream>>>(x, row_ptr, csr_src, csr_w, dinv, bufA, n);
  gemm_kernel<DIN, true><<<ggrid, 256, 0, stream>>>(bufA, W1, b1, bufB, n);
  // layer 2
  agg_kernel<HIDW><<<ab, 256, 0, stream>>>(bufB, row_ptr, csr_src, csr_w, dinv, bufA, n);
  gemm_kernel<HIDW, true><<<ggrid, 256, 0, stream>>>(bufA, W2, b2, bufB, n);
  // layer 3
  agg_kernel<HIDW><<<ab, 256, 0, stream>>>(bufB, row_ptr, csr_src, csr_w, dinv, bufA, n);
  gemm_kernel<HIDW, true><<<ggrid, 256, 0, stream>>>(bufA, W3, b3, bufB, n);  // h3 -> bufB
  // gate pre-activation: g = h3 @ Wg + bg  -> bufA
  gemm_kernel<HIDW, false><<<ggrid, 256, 0, stream>>>(bufB, Wg, bg, bufA, n);
  // gated mean-pool
  dim3 pgrid(NG, 4);
  pool_kernel<<<pgrid, 64, 0, stream>>>(bufB, bufA, gs, pooled);
  // classifier
  classifier_kernel<<<NG, 256, 0, stream>>>(pooled, Wc1, bc1, Wc2, bc2, out);
}

// Round 2
// 713.222 us; speedup vs baseline: 1.7305x; 1.7305x over previous
//
#include <hip/hip_runtime.h>

#define NG 64
#define HIDW 200
#define DIN 128
#define POOL_NC 8

// ---------------- degree / CSR build ----------------

__global__ void count_kernel(const int* __restrict__ dst, int* __restrict__ counts, int E) {
  int e = blockIdx.x * 256 + threadIdx.x;
  if (e < E) atomicAdd(&counts[dst[e]], 1);
}

__global__ void dinv_kernel(const int* __restrict__ counts, float* __restrict__ dinv, int n) {
  int i = blockIdx.x * 256 + threadIdx.x;
  if (i < n) dinv[i] = rsqrtf((float)(counts[i] + 1));  // +1 self-loop, always >=1
}

__global__ __launch_bounds__(1024) void scan_kernel(const int* __restrict__ counts,
                                                    int* __restrict__ row_ptr, int n) {
  __shared__ int ssum[1024];
  int tid = threadIdx.x;
  int per = (n + 1023) / 1024;
  int start = tid * per;
  int end = start + per; if (end > n) end = n;
  int s = 0;
  for (int i = start; i < end; ++i) s += counts[i];
  ssum[tid] = s;
  __syncthreads();
  for (int off = 1; off < 1024; off <<= 1) {
    int v = 0;
    if (tid >= off) v = ssum[tid - off];
    __syncthreads();
    if (tid >= off) ssum[tid] += v;
    __syncthreads();
  }
  int run = ssum[tid] - s;  // exclusive prefix of this thread's chunk
  for (int i = start; i < end; ++i) { row_ptr[i] = run; run += counts[i]; }
  if (tid == 1023) row_ptr[n] = ssum[1023];
}

__global__ void fill_kernel(const int* __restrict__ src, const int* __restrict__ dst,
                            const int* __restrict__ row_ptr, int* __restrict__ fill,
                            const float* __restrict__ dinv,
                            int* __restrict__ csr_src, float* __restrict__ csr_w, int E) {
  int e = blockIdx.x * 256 + threadIdx.x;
  if (e >= E) return;
  int d = dst[e];
  int pos = row_ptr[d] + atomicAdd(&fill[d], 1);
  int s = src[e];
  csr_src[pos] = s;
  csr_w[pos] = dinv[s];
}

__global__ void gstart_kernel(const int* __restrict__ batch, int* __restrict__ gs, int n) {
  int i = blockIdx.x * 256 + threadIdx.x;
  if (i >= n) return;
  int b = batch[i];
  if (i == 0) {
    for (int g = 0; g <= b; ++g) gs[g] = 0;
  } else {
    int bp = batch[i - 1];
    for (int g = bp + 1; g <= b; ++g) gs[g] = i;
  }
  if (i == n - 1) {
    for (int g = b + 1; g <= NG; ++g) gs[g] = n;
  }
}

// ---------------- aggregation: out = D^-1/2 (Adj+I) D^-1/2 h ----------------
// one wave per node; lane handles a float4 feature chunk

template <int D>
__global__ __launch_bounds__(256) void agg_kernel(const float* __restrict__ h,
                                                  const int* __restrict__ row_ptr,
                                                  const int* __restrict__ csr_src,
                                                  const float* __restrict__ csr_w,
                                                  const float* __restrict__ dinv,
                                                  float* __restrict__ out, int n) {
  constexpr int C = D / 4;
  int node = blockIdx.x * 4 + (threadIdx.x >> 6);
  int lane = threadIdx.x & 63;
  if (node >= n || lane >= C) return;
  const float4* hp = (const float4*)h;
  float di = dinv[node];
  int e0 = row_ptr[node], e1 = row_ptr[node + 1];
  float4 self = hp[(long)node * C + lane];
  float ax = di * self.x, ay = di * self.y, az = di * self.z, aw = di * self.w;
  for (int e = e0; e < e1; ++e) {
    int s = csr_src[e];
    float w = csr_w[e];
    float4 v = hp[(long)s * C + lane];
    ax = fmaf(w, v.x, ax);
    ay = fmaf(w, v.y, ay);
    az = fmaf(w, v.z, az);
    aw = fmaf(w, v.w, aw);
  }
  float4 r; r.x = di * ax; r.y = di * ay; r.z = di * az; r.w = di * aw;
  ((float4*)out)[(long)node * C + lane] = r;
}

// ---------------- fp32 GEMM: out[N][200] = A[N][K] @ W[K][200] + b ----------------
// BM=128, BN=128 (grid.y=2), Kt=32, 256 threads, per-thread 8x8 via split-float4.
// As is k-major (transposed) with LDA=129; Bs row-major [32][128].
// MODE: 0 = linear, 1 = relu, 2 = gated output (A[row][col] * sigmoid(acc+bias))

template <int K, int MODE>
__global__ __launch_bounds__(256) void gemm_kernel(const float* __restrict__ A,
                                                   const float* __restrict__ W,
                                                   const float* __restrict__ bias,
                                                   float* __restrict__ out, int N) {
  const int M = HIDW;
  __shared__ float As[32][129];   // [k][row], LDA=129
  __shared__ float Bs[32][128];   // [k][col]
  int row0 = blockIdx.x * 128;
  int col0 = blockIdx.y * 128;
  int tid = threadIdx.x;
  int tx = tid & 15;   // col group
  int ty = tid >> 4;   // row group
  float acc[8][8] = {{0.f}};

  for (int k0 = 0; k0 < K; k0 += 32) {
    // stage A: 128 rows x 32 k, transposed into As[k][row]
#pragma unroll
    for (int i = 0; i < 4; ++i) {
      int g = tid + i * 256;          // 1024 float4 groups
      int r = g >> 3, c4 = g & 7;     // r<128, c4<8
      int row = row0 + r;
      float4 v = {0.f, 0.f, 0.f, 0.f};
      if (row < N) {
        int kbase = k0 + c4 * 4;
        const float* ap = &A[(long)row * K + kbase];
        if (kbase + 3 < K) v = *(const float4*)ap;
        else {
          if (kbase + 0 < K) v.x = ap[0];
          if (kbase + 1 < K) v.y = ap[1];
          if (kbase + 2 < K) v.z = ap[2];
          if (kbase + 3 < K) v.w = ap[3];
        }
      }
      As[c4 * 4 + 0][r] = v.x;
      As[c4 * 4 + 1][r] = v.y;
      As[c4 * 4 + 2][r] = v.z;
      As[c4 * 4 + 3][r] = v.w;
    }
    // stage B: 32 k x 128 cols
#pragma unroll
    for (int i = 0; i < 4; ++i) {
      int g = tid + i * 256;          // 1024 float4 groups
      int r = g >> 5, c4 = g & 31;    // r<32, c4<32
      int k = k0 + r;
      int col = col0 + c4 * 4;
      float4 v = {0.f, 0.f, 0.f, 0.f};
      if (k < K) {
        const float* wp = &W[(long)k * M + col];
        if (col + 3 < M) v = *(const float4*)wp;
        else {
          if (col + 0 < M) v.x = wp[0];
          if (col + 1 < M) v.y = wp[1];
          if (col + 2 < M) v.z = wp[2];
          if (col + 3 < M) v.w = wp[3];
        }
      }
      *(float4*)&Bs[r][c4 * 4] = v;
    }
    __syncthreads();

#pragma unroll 8
    for (int k = 0; k < 32; ++k) {
      float4 a0 = *(const float4*)&As[k][ty * 4];
      float4 a1 = *(const float4*)&As[k][64 + ty * 4];
      float4 b0 = *(const float4*)&Bs[k][tx * 4];
      float4 b1 = *(const float4*)&Bs[k][64 + tx * 4];
      float av[8] = {a0.x, a0.y, a0.z, a0.w, a1.x, a1.y, a1.z, a1.w};
      float bv[8] = {b0.x, b0.y, b0.z, b0.w, b1.x, b1.y, b1.z, b1.w};
#pragma unroll
      for (int i = 0; i < 8; ++i)
#pragma unroll
        for (int j = 0; j < 8; ++j) acc[i][j] = fmaf(av[i], bv[j], acc[i][j]);
    }
    __syncthreads();
  }

#pragma unroll
  for (int i = 0; i < 8; ++i) {
    int row = row0 + ((i < 4) ? (ty * 4 + i) : (64 + ty * 4 + i - 4));
    if (row >= N) continue;
#pragma unroll
    for (int j = 0; j < 8; ++j) {
      int col = col0 + ((j < 4) ? (tx * 4 + j) : (64 + tx * 4 + j - 4));
      if (col < M) {
        float v = acc[i][j] + bias[col];
        if (MODE == 1) v = fmaxf(v, 0.f);
        if (MODE == 2) {
          // gated: out = h3[row][col] * sigmoid(v); A IS h3 (K == M == 200)
          float h = A[(long)row * K + col];
          v = h * (1.f / (1.f + __expf(-v)));
        }
        out[(long)row * M + col] = v;
      }
    }
  }
}

// ---------------- mean pool over gated features (two-stage, deterministic) -----------

__global__ __launch_bounds__(256) void pool_partial_kernel(const float* __restrict__ gated,
                                                           const int* __restrict__ gs,
                                                           float* __restrict__ partial) {
  int g = blockIdx.x;
  int c = blockIdx.y;
  int f = threadIdx.x;
  int s = gs[g], e = gs[g + 1];
  int len = e - s;
  int chunk = (len + POOL_NC - 1) / POOL_NC;
  int i0 = s + c * chunk;
  int i1 = i0 + chunk; if (i1 > e) i1 = e;
  float acc = 0.f;
  if (f < HIDW) {
    for (int i = i0; i < i1; ++i) acc += gated[(long)i * HIDW + f];
  }
  if (f < HIDW) partial[(g * POOL_NC + c) * HIDW + f] = acc;
}

__global__ __launch_bounds__(256) void pool_final_kernel(const float* __restrict__ partial,
                                                         const int* __restrict__ gs,
                                                         float* __restrict__ pooled) {
  int g = blockIdx.x;
  int f = threadIdx.x;
  if (f >= HIDW) return;
  float acc = 0.f;
#pragma unroll
  for (int c = 0; c < POOL_NC; ++c) acc += partial[(g * POOL_NC + c) * HIDW + f];
  float cnt = fmaxf((float)(gs[g + 1] - gs[g]), 1.f);
  pooled[g * HIDW + f] = acc / cnt;
}

// ---------------- classifier: relu(pooled@Wc1+bc1)@Wc2+bc2 ----------------

__global__ void classifier_kernel(const float* __restrict__ pooled,
                                  const float* __restrict__ Wc1, const float* __restrict__ bc1,
                                  const float* __restrict__ Wc2, const float* __restrict__ bc2,
                                  float* __restrict__ out) {
  int g = blockIdx.x;
  int tid = threadIdx.x;
  __shared__ float pg[HIDW];
  __shared__ float hid[100];
  if (tid < HIDW) pg[tid] = pooled[g * HIDW + tid];
  __syncthreads();
  if (tid < 100) {
    float a = bc1[tid];
    for (int k = 0; k < HIDW; ++k) a = fmaf(pg[k], Wc1[k * 100 + tid], a);
    hid[tid] = fmaxf(a, 0.f);
  }
  __syncthreads();
  if (tid < 2) {
    float a = bc2[tid];
    for (int k = 0; k < 100; ++k) a = fmaf(hid[k], Wc2[k * 2 + tid], a);
    out[g * 2 + tid] = a;
  }
}

// ---------------- launch ----------------

extern "C" void kernel_launch(void* const* d_in, const int* in_sizes, int n_in,
                              void* d_out, int out_size, void* d_ws, size_t ws_size,
                              hipStream_t stream) {
  const float* x    = (const float*)d_in[0];
  const int*   ei   = (const int*)d_in[1];
  const int*   batch= (const int*)d_in[2];
  const float* W1 = (const float*)d_in[3];  const float* b1 = (const float*)d_in[4];
  const float* W2 = (const float*)d_in[5];  const float* b2 = (const float*)d_in[6];
  const float* W3 = (const float*)d_in[7];  const float* b3 = (const float*)d_in[8];
  const float* Wg = (const float*)d_in[9];  const float* bg = (const float*)d_in[10];
  const float* Wc1= (const float*)d_in[11]; const float* bc1= (const float*)d_in[12];
  const float* Wc2= (const float*)d_in[13]; const float* bc2= (const float*)d_in[14];
  float* out = (float*)d_out;

  const int n = in_sizes[0] / DIN;     // 40000
  const int E = in_sizes[1] / 2;       // 640000
  const int* src = ei;
  const int* dst = ei + E;

  // workspace carve-up (float4-aligned)
  int* counts   = (int*)d_ws;               // n
  int* fill     = counts + n;               // n
  int* row_ptr  = fill + n;                 // n+1 (pad to n+4)
  int* gs       = row_ptr + (n + 4);        // 65 (pad to 68)
  float* dinv   = (float*)(gs + 68);        // n
  int* csr_src  = (int*)(dinv + n);         // E
  float* csr_w  = (float*)(csr_src + E);    // E
  float* pooled = csr_w + E;                // 64*200
  float* partial= pooled + NG * HIDW;       // 64*8*200
  float* bufA   = partial + NG * POOL_NC * HIDW;  // n*200
  float* bufB   = bufA + (long)n * HIDW;          // n*200

  hipMemsetAsync(counts, 0, (size_t)2 * n * sizeof(int), stream);  // counts + fill

  int eb = (E + 255) / 256;
  int nb = (n + 255) / 256;
  count_kernel<<<eb, 256, 0, stream>>>(dst, counts, E);
  dinv_kernel<<<nb, 256, 0, stream>>>(counts, dinv, n);
  scan_kernel<<<1, 1024, 0, stream>>>(counts, row_ptr, n);
  fill_kernel<<<eb, 256, 0, stream>>>(src, dst, row_ptr, fill, dinv, csr_src, csr_w, E);
  gstart_kernel<<<nb, 256, 0, stream>>>(batch, gs, n);

  int ab = (n + 3) / 4;
  dim3 ggrid((n + 127) / 128, 2);

  // layer 1: agg(x) [D=128] -> gemm K=128
  agg_kernel<DIN><<<ab, 256, 0, stream>>>(x, row_ptr, csr_src, csr_w, dinv, bufA, n);
  gemm_kernel<DIN, 1><<<ggrid, 256, 0, stream>>>(bufA, W1, b1, bufB, n);
  // layer 2
  agg_kernel<HIDW><<<ab, 256, 0, stream>>>(bufB, row_ptr, csr_src, csr_w, dinv, bufA, n);
  gemm_kernel<HIDW, 1><<<ggrid, 256, 0, stream>>>(bufA, W2, b2, bufB, n);
  // layer 3
  agg_kernel<HIDW><<<ab, 256, 0, stream>>>(bufB, row_ptr, csr_src, csr_w, dinv, bufA, n);
  gemm_kernel<HIDW, 1><<<ggrid, 256, 0, stream>>>(bufA, W3, b3, bufB, n);  // h3 -> bufB
  // gate + apply: bufA = h3 * sigmoid(h3 @ Wg + bg)
  gemm_kernel<HIDW, 2><<<ggrid, 256, 0, stream>>>(bufB, Wg, bg, bufA, n);
  // mean-pool (two-stage deterministic)
  dim3 pgrid(NG, POOL_NC);
  pool_partial_kernel<<<pgrid, 256, 0, stream>>>(bufA, gs, partial);
  pool_final_kernel<<<NG, 256, 0, stream>>>(partial, gs, pooled);
  // classifier
  classifier_kernel<<<NG, 256, 0, stream>>>(pooled, Wc1, bc1, Wc2, bc2, out);
}

// Round 3
// 690.461 us; speedup vs baseline: 1.7876x; 1.0330x over previous
//
#include <hip/hip_runtime.h>

#define NG 64
#define HIDW 200
#define DIN 128
#define POOL_NC 8

typedef _Float16 half4 __attribute__((ext_vector_type(4)));
typedef _Float16 half8 __attribute__((ext_vector_type(8)));
typedef float floatx4 __attribute__((ext_vector_type(4)));

// ---------------- degree / CSR build ----------------

__global__ void count_kernel(const int* __restrict__ dst, int* __restrict__ counts, int E) {
  int e = blockIdx.x * 256 + threadIdx.x;
  if (e < E) atomicAdd(&counts[dst[e]], 1);
}

__global__ void dinv_kernel(const int* __restrict__ counts, float* __restrict__ dinv, int n) {
  int i = blockIdx.x * 256 + threadIdx.x;
  if (i < n) dinv[i] = rsqrtf((float)(counts[i] + 1));  // +1 self-loop, always >=1
}

__global__ __launch_bounds__(1024) void scan_kernel(const int* __restrict__ counts,
                                                    int* __restrict__ row_ptr, int n) {
  __shared__ int ssum[1024];
  int tid = threadIdx.x;
  int per = (n + 1023) / 1024;
  int start = tid * per;
  int end = start + per; if (end > n) end = n;
  int s = 0;
  for (int i = start; i < end; ++i) s += counts[i];
  ssum[tid] = s;
  __syncthreads();
  for (int off = 1; off < 1024; off <<= 1) {
    int v = 0;
    if (tid >= off) v = ssum[tid - off];
    __syncthreads();
    if (tid >= off) ssum[tid] += v;
    __syncthreads();
  }
  int run = ssum[tid] - s;  // exclusive prefix of this thread's chunk
  for (int i = start; i < end; ++i) { row_ptr[i] = run; run += counts[i]; }
  if (tid == 1023) row_ptr[n] = ssum[1023];
}

__global__ void fill_kernel(const int* __restrict__ src, const int* __restrict__ dst,
                            const int* __restrict__ row_ptr, int* __restrict__ fill,
                            const float* __restrict__ dinv,
                            int* __restrict__ csr_src, float* __restrict__ csr_w, int E) {
  int e = blockIdx.x * 256 + threadIdx.x;
  if (e >= E) return;
  int d = dst[e];
  int pos = row_ptr[d] + atomicAdd(&fill[d], 1);
  int s = src[e];
  csr_src[pos] = s;
  csr_w[pos] = dinv[s];
}

__global__ void gstart_kernel(const int* __restrict__ batch, int* __restrict__ gs, int n) {
  int i = blockIdx.x * 256 + threadIdx.x;
  if (i >= n) return;
  int b = batch[i];
  if (i == 0) {
    for (int g = 0; g <= b; ++g) gs[g] = 0;
  } else {
    int bp = batch[i - 1];
    for (int g = bp + 1; g <= b; ++g) gs[g] = i;
  }
  if (i == n - 1) {
    for (int g = b + 1; g <= NG; ++g) gs[g] = n;
  }
}

// ---------------- weight prep: W[k][200] fp32 -> WT_h/WT_l [224][KP] f16 ----------------
// split: W = Wh + Wl (two f16 terms ~ exact fp32); transposed col-major for B frags

__global__ void wprep_kernel(const float* __restrict__ W, _Float16* __restrict__ WTh,
                             _Float16* __restrict__ WTl, int K, int KP) {
  int idx = blockIdx.x * 256 + threadIdx.x;
  if (idx >= 224 * KP) return;
  int col = idx / KP, k = idx % KP;
  float v = (col < HIDW && k < K) ? W[(long)k * HIDW + col] : 0.f;
  _Float16 h = (_Float16)v;
  WTh[idx] = h;
  WTl[idx] = (_Float16)(v - (float)h);
}

// ---------------- aggregation: out = D^-1/2 (Adj+I) D^-1/2 h ----------------
// one wave per node; lane handles a float4 feature chunk

template <int D>
__global__ __launch_bounds__(256) void agg_kernel(const float* __restrict__ h,
                                                  const int* __restrict__ row_ptr,
                                                  const int* __restrict__ csr_src,
                                                  const float* __restrict__ csr_w,
                                                  const float* __restrict__ dinv,
                                                  float* __restrict__ out, int n) {
  constexpr int C = D / 4;
  int node = blockIdx.x * 4 + (threadIdx.x >> 6);
  int lane = threadIdx.x & 63;
  if (node >= n || lane >= C) return;
  const float4* hp = (const float4*)h;
  float di = dinv[node];
  int e0 = row_ptr[node], e1 = row_ptr[node + 1];
  float4 self = hp[(long)node * C + lane];
  float ax = di * self.x, ay = di * self.y, az = di * self.z, aw = di * self.w;
  for (int e = e0; e < e1; ++e) {
    int s = csr_src[e];
    float w = csr_w[e];
    float4 v = hp[(long)s * C + lane];
    ax = fmaf(w, v.x, ax);
    ay = fmaf(w, v.y, ay);
    az = fmaf(w, v.z, az);
    aw = fmaf(w, v.w, aw);
  }
  float4 r; r.x = di * ax; r.y = di * ay; r.z = di * az; r.w = di * aw;
  ((float4*)out)[(long)node * C + lane] = r;
}

// ---------------- MFMA GEMM: out[N][200] = A[N][K] @ W[K][200] + b ----------------
// fp16 MFMA 16x16x32, fp32 accum, 2-term W split (A*Wh + A*Wl).
// BM=128, BN=224 (cols 0..199 valid), 4 waves in 2x2, wave tile 64x112 = 4x7 frags.
// LDS stride 40 f16 = 80B: 16B-aligned b128 frag reads, 2-way banking (free, m136).
// MODE: 0 = linear, 1 = relu, 2 = gated (A[row][col] * sigmoid(acc+bias), A==h3)

template <int K, int KP, int MODE>
__global__ __launch_bounds__(256) void mgemm_kernel(const float* __restrict__ A,
                                                    const _Float16* __restrict__ WTh,
                                                    const _Float16* __restrict__ WTl,
                                                    const float* __restrict__ bias,
                                                    float* __restrict__ out, int N) {
  __shared__ _Float16 As[128][40];
  __shared__ _Float16 Bhs[224][40];
  __shared__ _Float16 Bls[224][40];
  int row0 = blockIdx.x * 128;
  int tid = threadIdx.x;
  int lane = tid & 63;
  int wid = tid >> 6;
  int wr = wid >> 1;   // row half (64 rows)
  int wc = wid & 1;    // col half (112 cols)
  int l15 = lane & 15;
  int lq = lane >> 4;  // k-quarter: 8 contiguous f16

  floatx4 acc[4][7];
#pragma unroll
  for (int i = 0; i < 4; ++i)
#pragma unroll
    for (int j = 0; j < 7; ++j) acc[i][j] = (floatx4){0.f, 0.f, 0.f, 0.f};

  const int KSTEPS = (K + 31) / 32;
  for (int ks = 0; ks < KSTEPS; ++ks) {
    int k0 = ks * 32;
    // stage A: 128 rows x 32 k, fp32 -> f16 (row-major, k-contiguous)
#pragma unroll
    for (int i = 0; i < 4; ++i) {
      int g = tid + i * 256;          // 1024 float4 units
      int r = g >> 3, c4 = g & 7;
      int row = row0 + r;
      int kb = k0 + c4 * 4;
      float4 v = {0.f, 0.f, 0.f, 0.f};
      if (row < N && kb < K) v = *(const float4*)&A[(long)row * K + kb];
      half4 hv = {(_Float16)v.x, (_Float16)v.y, (_Float16)v.z, (_Float16)v.w};
      *(half4*)&As[r][c4 * 4] = hv;
    }
    // stage B: 224 cols x 32 k from pre-transposed f16 (coalesced 16B loads)
#pragma unroll
    for (int i = 0; i < 4; ++i) {
      int g = tid + i * 256;          // 896 used
      if (g < 896) {
        int col = g >> 2, kc = g & 3;
        *(half8*)&Bhs[col][kc * 8] = *(const half8*)&WTh[(long)col * KP + k0 + kc * 8];
        *(half8*)&Bls[col][kc * 8] = *(const half8*)&WTl[(long)col * KP + k0 + kc * 8];
      }
    }
    __syncthreads();

    half8 af[4];
#pragma unroll
    for (int rf = 0; rf < 4; ++rf)
      af[rf] = *(const half8*)&As[wr * 64 + rf * 16 + l15][lq * 8];
#pragma unroll
    for (int cf = 0; cf < 7; ++cf) {
      half8 bh = *(const half8*)&Bhs[wc * 112 + cf * 16 + l15][lq * 8];
      half8 bl = *(const half8*)&Bls[wc * 112 + cf * 16 + l15][lq * 8];
#pragma unroll
      for (int rf = 0; rf < 4; ++rf) {
        acc[rf][cf] = __builtin_amdgcn_mfma_f32_16x16x32_f16(af[rf], bh, acc[rf][cf], 0, 0, 0);
        acc[rf][cf] = __builtin_amdgcn_mfma_f32_16x16x32_f16(af[rf], bl, acc[rf][cf], 0, 0, 0);
      }
    }
    __syncthreads();
  }

  // epilogue: C frag mapping col=lane&15, row=(lane>>4)*4+reg  [m89]
#pragma unroll
  for (int cf = 0; cf < 7; ++cf) {
    int col = wc * 112 + cf * 16 + l15;
    if (col >= HIDW) continue;
    float bs = bias[col];
#pragma unroll
    for (int rf = 0; rf < 4; ++rf) {
      int rbase = row0 + wr * 64 + rf * 16 + lq * 4;
#pragma unroll
      for (int j = 0; j < 4; ++j) {
        int row = rbase + j;
        if (row >= N) continue;
        float v = acc[rf][cf][j] + bs;
        if (MODE == 1) v = fmaxf(v, 0.f);
        if (MODE == 2) {
          float hv = A[(long)row * K + col];  // A IS h3 (K == 200)
          v = hv * (1.f / (1.f + __expf(-v)));
        }
        out[(long)row * HIDW + col] = v;
      }
    }
  }
}

// ---------------- mean pool over gated features (two-stage, deterministic) -----------

__global__ __launch_bounds__(256) void pool_partial_kernel(const float* __restrict__ gated,
                                                           const int* __restrict__ gs,
                                                           float* __restrict__ partial) {
  int g = blockIdx.x;
  int c = blockIdx.y;
  int f = threadIdx.x;
  int s = gs[g], e = gs[g + 1];
  int len = e - s;
  int chunk = (len + POOL_NC - 1) / POOL_NC;
  int i0 = s + c * chunk;
  int i1 = i0 + chunk; if (i1 > e) i1 = e;
  float acc = 0.f;
  if (f < HIDW) {
    for (int i = i0; i < i1; ++i) acc += gated[(long)i * HIDW + f];
  }
  if (f < HIDW) partial[(g * POOL_NC + c) * HIDW + f] = acc;
}

__global__ __launch_bounds__(256) void pool_final_kernel(const float* __restrict__ partial,
                                                         const int* __restrict__ gs,
                                                         float* __restrict__ pooled) {
  int g = blockIdx.x;
  int f = threadIdx.x;
  if (f >= HIDW) return;
  float acc = 0.f;
#pragma unroll
  for (int c = 0; c < POOL_NC; ++c) acc += partial[(g * POOL_NC + c) * HIDW + f];
  float cnt = fmaxf((float)(gs[g + 1] - gs[g]), 1.f);
  pooled[g * HIDW + f] = acc / cnt;
}

// ---------------- classifier: relu(pooled@Wc1+bc1)@Wc2+bc2 ----------------

__global__ void classifier_kernel(const float* __restrict__ pooled,
                                  const float* __restrict__ Wc1, const float* __restrict__ bc1,
                                  const float* __restrict__ Wc2, const float* __restrict__ bc2,
                                  float* __restrict__ out) {
  int g = blockIdx.x;
  int tid = threadIdx.x;
  __shared__ float pg[HIDW];
  __shared__ float hid[100];
  if (tid < HIDW) pg[tid] = pooled[g * HIDW + tid];
  __syncthreads();
  if (tid < 100) {
    float a = bc1[tid];
    for (int k = 0; k < HIDW; ++k) a = fmaf(pg[k], Wc1[k * 100 + tid], a);
    hid[tid] = fmaxf(a, 0.f);
  }
  __syncthreads();
  if (tid < 2) {
    float a = bc2[tid];
    for (int k = 0; k < 100; ++k) a = fmaf(hid[k], Wc2[k * 2 + tid], a);
    out[g * 2 + tid] = a;
  }
}

// ---------------- launch ----------------

extern "C" void kernel_launch(void* const* d_in, const int* in_sizes, int n_in,
                              void* d_out, int out_size, void* d_ws, size_t ws_size,
                              hipStream_t stream) {
  const float* x    = (const float*)d_in[0];
  const int*   ei   = (const int*)d_in[1];
  const int*   batch= (const int*)d_in[2];
  const float* W1 = (const float*)d_in[3];  const float* b1 = (const float*)d_in[4];
  const float* W2 = (const float*)d_in[5];  const float* b2 = (const float*)d_in[6];
  const float* W3 = (const float*)d_in[7];  const float* b3 = (const float*)d_in[8];
  const float* Wg = (const float*)d_in[9];  const float* bg = (const float*)d_in[10];
  const float* Wc1= (const float*)d_in[11]; const float* bc1= (const float*)d_in[12];
  const float* Wc2= (const float*)d_in[13]; const float* bc2= (const float*)d_in[14];
  float* out = (float*)d_out;

  const int n = in_sizes[0] / DIN;     // 40000
  const int E = in_sizes[1] / 2;       // 640000
  const int* src = ei;
  const int* dst = ei + E;

  // workspace carve-up (16B-aligned segments)
  int* counts   = (int*)d_ws;               // n
  int* fill     = counts + n;               // n
  int* row_ptr  = fill + n;                 // n+1 (pad to n+4)
  int* gs       = row_ptr + (n + 4);        // 65 (pad to 68)
  float* dinv   = (float*)(gs + 68);        // n
  int* csr_src  = (int*)(dinv + n);         // E
  float* csr_w  = (float*)(csr_src + E);    // E
  float* pooled = csr_w + E;                // 64*200
  float* partial= pooled + NG * HIDW;       // 64*8*200
  _Float16* wt1h = (_Float16*)(partial + NG * POOL_NC * HIDW);  // 224*128
  _Float16* wt1l = wt1h + 224 * 128;
  _Float16* wt2h = wt1l + 224 * 128;        // 224*224 each from here
  _Float16* wt2l = wt2h + 224 * 224;
  _Float16* wt3h = wt2l + 224 * 224;
  _Float16* wt3l = wt3h + 224 * 224;
  _Float16* wtgh = wt3l + 224 * 224;
  _Float16* wtgl = wtgh + 224 * 224;
  float* bufA   = (float*)(wtgl + 224 * 224);   // n*200
  float* bufB   = bufA + (long)n * HIDW;        // n*200

  hipMemsetAsync(counts, 0, (size_t)2 * n * sizeof(int), stream);  // counts + fill

  // weight prep (independent of graph build)
  wprep_kernel<<<(224 * 128 + 255) / 256, 256, 0, stream>>>(W1, wt1h, wt1l, 128, 128);
  wprep_kernel<<<(224 * 224 + 255) / 256, 256, 0, stream>>>(W2, wt2h, wt2l, 200, 224);
  wprep_kernel<<<(224 * 224 + 255) / 256, 256, 0, stream>>>(W3, wt3h, wt3l, 200, 224);
  wprep_kernel<<<(224 * 224 + 255) / 256, 256, 0, stream>>>(Wg, wtgh, wtgl, 200, 224);

  int eb = (E + 255) / 256;
  int nb = (n + 255) / 256;
  count_kernel<<<eb, 256, 0, stream>>>(dst, counts, E);
  dinv_kernel<<<nb, 256, 0, stream>>>(counts, dinv, n);
  scan_kernel<<<1, 1024, 0, stream>>>(counts, row_ptr, n);
  fill_kernel<<<eb, 256, 0, stream>>>(src, dst, row_ptr, fill, dinv, csr_src, csr_w, E);
  gstart_kernel<<<nb, 256, 0, stream>>>(batch, gs, n);

  int ab = (n + 3) / 4;
  int gb = (n + 127) / 128;  // 313

  // layer 1: agg(x) [D=128] -> gemm K=128
  agg_kernel<DIN><<<ab, 256, 0, stream>>>(x, row_ptr, csr_src, csr_w, dinv, bufA, n);
  mgemm_kernel<DIN, 128, 1><<<gb, 256, 0, stream>>>(bufA, wt1h, wt1l, b1, bufB, n);
  // layer 2
  agg_kernel<HIDW><<<ab, 256, 0, stream>>>(bufB, row_ptr, csr_src, csr_w, dinv, bufA, n);
  mgemm_kernel<HIDW, 224, 1><<<gb, 256, 0, stream>>>(bufA, wt2h, wt2l, b2, bufB, n);
  // layer 3
  agg_kernel<HIDW><<<ab, 256, 0, stream>>>(bufB, row_ptr, csr_src, csr_w, dinv, bufA, n);
  mgemm_kernel<HIDW, 224, 1><<<gb, 256, 0, stream>>>(bufA, wt3h, wt3l, b3, bufB, n);  // h3
  // gate + apply: bufA = h3 * sigmoid(h3 @ Wg + bg)
  mgemm_kernel<HIDW, 224, 2><<<gb, 256, 0, stream>>>(bufB, wtgh, wtgl, bg, bufA, n);
  // mean-pool (two-stage deterministic)
  dim3 pgrid(NG, POOL_NC);
  pool_partial_kernel<<<pgrid, 256, 0, stream>>>(bufA, gs, partial);
  pool_final_kernel<<<NG, 256, 0, stream>>>(partial, gs, pooled);
  // classifier
  classifier_kernel<<<NG, 256, 0, stream>>>(pooled, Wc1, bc1, Wc2, bc2, out);
}

// Round 4
// 522.136 us; speedup vs baseline: 2.3639x; 1.3224x over previous
//
#include <hip/hip_runtime.h>

#define NG 64
#define HIDW 200
#define DIN 128
#define KPAD 224
#define POOL_NC 8

typedef _Float16 half4_t __attribute__((ext_vector_type(4)));
typedef _Float16 half8_t __attribute__((ext_vector_type(8)));
typedef float floatx4 __attribute__((ext_vector_type(4)));

// ---------------- degree / CSR build ----------------

__global__ void count_kernel(const int* __restrict__ dst, int* __restrict__ counts, int E) {
  int e = blockIdx.x * 256 + threadIdx.x;
  if (e < E) atomicAdd(&counts[dst[e]], 1);
}

__global__ void dinv_kernel(const int* __restrict__ counts, float* __restrict__ dinv, int n) {
  int i = blockIdx.x * 256 + threadIdx.x;
  if (i < n) dinv[i] = rsqrtf((float)(counts[i] + 1));  // +1 self-loop
}

__global__ __launch_bounds__(1024) void scan_kernel(const int* __restrict__ counts,
                                                    int* __restrict__ row_ptr, int n) {
  __shared__ int ssum[1024];
  int tid = threadIdx.x;
  int per = (n + 1023) / 1024;
  int start = tid * per;
  int end = start + per; if (end > n) end = n;
  int s = 0;
  for (int i = start; i < end; ++i) s += counts[i];
  ssum[tid] = s;
  __syncthreads();
  for (int off = 1; off < 1024; off <<= 1) {
    int v = 0;
    if (tid >= off) v = ssum[tid - off];
    __syncthreads();
    if (tid >= off) ssum[tid] += v;
    __syncthreads();
  }
  int run = ssum[tid] - s;
  for (int i = start; i < end; ++i) { row_ptr[i] = run; run += counts[i]; }
  if (tid == 1023) row_ptr[n] = ssum[1023];
}

__global__ void fill_kernel(const int* __restrict__ src, const int* __restrict__ dst,
                            const int* __restrict__ row_ptr, int* __restrict__ fill,
                            const float* __restrict__ dinv,
                            int* __restrict__ csr_src, float* __restrict__ csr_w, int E) {
  int e = blockIdx.x * 256 + threadIdx.x;
  if (e >= E) return;
  int d = dst[e];
  int pos = row_ptr[d] + atomicAdd(&fill[d], 1);
  int s = src[e];
  csr_src[pos] = s;
  csr_w[pos] = dinv[s];
}

__global__ void gstart_kernel(const int* __restrict__ batch, int* __restrict__ gs, int n) {
  int i = blockIdx.x * 256 + threadIdx.x;
  if (i >= n) return;
  int b = batch[i];
  if (i == 0) {
    for (int g = 0; g <= b; ++g) gs[g] = 0;
  } else {
    int bp = batch[i - 1];
    for (int g = bp + 1; g <= b; ++g) gs[g] = i;
  }
  if (i == n - 1) {
    for (int g = b + 1; g <= NG; ++g) gs[g] = n;
  }
}

// ---------------- weight prep: W[k][200] fp32 -> WT_h/WT_l [224][KP] f16 ----------------

__global__ void wprep_kernel(const float* __restrict__ W, _Float16* __restrict__ WTh,
                             _Float16* __restrict__ WTl, int K, int KP) {
  int idx = blockIdx.x * 256 + threadIdx.x;
  if (idx >= 224 * KP) return;
  int col = idx / KP, k = idx % KP;
  float v = (col < HIDW && k < K) ? W[(long)k * HIDW + col] : 0.f;
  _Float16 h = (_Float16)v;
  WTh[idx] = h;
  WTl[idx] = (_Float16)(v - (float)h);
}

// ---------------- aggregation layer 1: x (f32,[n][128]) -> f16 [n][128] ----------------
// wave per node; lanes 0..31 each own a float4 chunk

__global__ __launch_bounds__(256) void aggx_kernel(const float* __restrict__ x,
                                                   const int* __restrict__ row_ptr,
                                                   const int* __restrict__ csr_src,
                                                   const float* __restrict__ csr_w,
                                                   const float* __restrict__ dinv,
                                                   _Float16* __restrict__ out, int n) {
  int node = blockIdx.x * 4 + (threadIdx.x >> 6);
  int lane = threadIdx.x & 63;
  if (node >= n || lane >= 32) return;
  const float4* hp = (const float4*)x;
  float di = dinv[node];
  int e0 = row_ptr[node], e1 = row_ptr[node + 1];
  float4 self = hp[(long)node * 32 + lane];
  float ax = di * self.x, ay = di * self.y, az = di * self.z, aw = di * self.w;
  for (int e = e0; e < e1; ++e) {
    int s = csr_src[e];
    float w = csr_w[e];
    float4 v = hp[(long)s * 32 + lane];
    ax = fmaf(w, v.x, ax); ay = fmaf(w, v.y, ay);
    az = fmaf(w, v.z, az); aw = fmaf(w, v.w, aw);
  }
  half4_t r = {(_Float16)(di * ax), (_Float16)(di * ay),
               (_Float16)(di * az), (_Float16)(di * aw)};
  ((half4_t*)out)[(long)node * 32 + lane] = r;
}

// ---------------- aggregation layers 2/3: f16 [n][224] -> f16 [n][224] ----------------
// wave per node; lanes 0..55 each own a half4 chunk (pads stay zero)

__global__ __launch_bounds__(256) void aggh_kernel(const _Float16* __restrict__ h,
                                                   const int* __restrict__ row_ptr,
                                                   const int* __restrict__ csr_src,
                                                   const float* __restrict__ csr_w,
                                                   const float* __restrict__ dinv,
                                                   _Float16* __restrict__ out, int n) {
  const int C = KPAD / 4;  // 56
  int node = blockIdx.x * 4 + (threadIdx.x >> 6);
  int lane = threadIdx.x & 63;
  if (node >= n || lane >= C) return;
  const half4_t* hp = (const half4_t*)h;
  float di = dinv[node];
  int e0 = row_ptr[node], e1 = row_ptr[node + 1];
  half4_t self = hp[(long)node * C + lane];
  float ax = di * (float)self.x, ay = di * (float)self.y;
  float az = di * (float)self.z, aw = di * (float)self.w;
  for (int e = e0; e < e1; ++e) {
    int s = csr_src[e];
    float w = csr_w[e];
    half4_t v = hp[(long)s * C + lane];
    ax = fmaf(w, (float)v.x, ax); ay = fmaf(w, (float)v.y, ay);
    az = fmaf(w, (float)v.z, az); aw = fmaf(w, (float)v.w, aw);
  }
  half4_t r = {(_Float16)(di * ax), (_Float16)(di * ay),
               (_Float16)(di * az), (_Float16)(di * aw)};
  ((half4_t*)out)[(long)node * C + lane] = r;
}

// ---------------- MFMA GEMM, no LDS, no barriers ----------------
// out[N][224] (f16) = relu/gate(A[N][KP] (f16) @ W + b). Wave tile 32x112:
// 2 row-frags x 7 col-frags, W split into Wh+Wl. A/B frags loaded directly from
// global (B is L2-resident: <=200 KB; A rows served by L1/L2).
// Frag mapping (verified R3): A/B lane l -> row/col = l&15, k = (l>>4)*8..+8;
// C lane l -> col = l&15, row = (l>>4)*4 + reg.
// MODE: 1 = relu, 2 = gated (A[row][col] * sigmoid(acc+bias), A==h3)

template <int KP, int MODE>
__global__ __launch_bounds__(256, 3) void mgemm_kernel(const _Float16* __restrict__ A,
                                                       const _Float16* __restrict__ WTh,
                                                       const _Float16* __restrict__ WTl,
                                                       const float* __restrict__ bias,
                                                       _Float16* __restrict__ out, int N) {
  int tid = threadIdx.x;
  int lane = tid & 63;
  int w = blockIdx.x * 4 + (tid >> 6);  // global wave id
  int wt = w >> 1;                      // row tile (32 rows)
  int wc = w & 1;                       // col half (112 cols)
  int row0 = wt * 32;
  if (row0 >= N) return;
  int l15 = lane & 15;
  int lq = lane >> 4;

  const _Float16* pa0 = A + (long)(row0 + l15) * KP + lq * 8;
  const _Float16* pa1 = pa0 + 16 * KP;
  const _Float16* pbh = WTh + (long)(wc * 112 + l15) * KP + lq * 8;
  const _Float16* pbl = WTl + (long)(wc * 112 + l15) * KP + lq * 8;

  floatx4 acc[2][7];
#pragma unroll
  for (int i = 0; i < 2; ++i)
#pragma unroll
    for (int j = 0; j < 7; ++j) acc[i][j] = (floatx4){0.f, 0.f, 0.f, 0.f};

  for (int k0 = 0; k0 < KP; k0 += 32) {
    half8_t a0 = *(const half8_t*)(pa0 + k0);
    half8_t a1 = *(const half8_t*)(pa1 + k0);
#pragma unroll
    for (int cf = 0; cf < 7; ++cf) {
      half8_t bh = *(const half8_t*)(pbh + (long)cf * 16 * KP + k0);
      half8_t bl = *(const half8_t*)(pbl + (long)cf * 16 * KP + k0);
      acc[0][cf] = __builtin_amdgcn_mfma_f32_16x16x32_f16(a0, bh, acc[0][cf], 0, 0, 0);
      acc[1][cf] = __builtin_amdgcn_mfma_f32_16x16x32_f16(a1, bh, acc[1][cf], 0, 0, 0);
      acc[0][cf] = __builtin_amdgcn_mfma_f32_16x16x32_f16(a0, bl, acc[0][cf], 0, 0, 0);
      acc[1][cf] = __builtin_amdgcn_mfma_f32_16x16x32_f16(a1, bl, acc[1][cf], 0, 0, 0);
    }
  }

#pragma unroll
  for (int cf = 0; cf < 7; ++cf) {
    int col = wc * 112 + cf * 16 + l15;
    float bs = (col < HIDW) ? bias[col] : 0.f;
#pragma unroll
    for (int rf = 0; rf < 2; ++rf) {
      int rbase = row0 + rf * 16 + lq * 4;
#pragma unroll
      for (int j = 0; j < 4; ++j) {
        int row = rbase + j;
        float v = acc[rf][cf][j] + bs;
        if (MODE == 1) v = fmaxf(v, 0.f);
        if (MODE == 2) {
          float hv = (float)A[(long)row * KP + col];
          v = hv * (1.f / (1.f + __expf(-v)));
        }
        if (col >= HIDW) v = 0.f;  // keep pads zero
        out[(long)row * KPAD + col] = (_Float16)v;
      }
    }
  }
}

// ---------------- mean pool over gated f16 features (two-stage, deterministic) --------

__global__ __launch_bounds__(256) void pool_partial_kernel(const _Float16* __restrict__ gated,
                                                           const int* __restrict__ gs,
                                                           float* __restrict__ partial) {
  int g = blockIdx.x;
  int c = blockIdx.y;
  int f = threadIdx.x;
  int s = gs[g], e = gs[g + 1];
  int len = e - s;
  int chunk = (len + POOL_NC - 1) / POOL_NC;
  int i0 = s + c * chunk;
  int i1 = i0 + chunk; if (i1 > e) i1 = e;
  if (f < HIDW) {
    float acc = 0.f;
    for (int i = i0; i < i1; ++i) acc += (float)gated[(long)i * KPAD + f];
    partial[(g * POOL_NC + c) * HIDW + f] = acc;
  }
}

__global__ __launch_bounds__(256) void pool_final_kernel(const float* __restrict__ partial,
                                                         const int* __restrict__ gs,
                                                         float* __restrict__ pooled) {
  int g = blockIdx.x;
  int f = threadIdx.x;
  if (f >= HIDW) return;
  float acc = 0.f;
#pragma unroll
  for (int c = 0; c < POOL_NC; ++c) acc += partial[(g * POOL_NC + c) * HIDW + f];
  float cnt = fmaxf((float)(gs[g + 1] - gs[g]), 1.f);
  pooled[g * HIDW + f] = acc / cnt;
}

// ---------------- classifier ----------------

__global__ void classifier_kernel(const float* __restrict__ pooled,
                                  const float* __restrict__ Wc1, const float* __restrict__ bc1,
                                  const float* __restrict__ Wc2, const float* __restrict__ bc2,
                                  float* __restrict__ out) {
  int g = blockIdx.x;
  int tid = threadIdx.x;
  __shared__ float pg[HIDW];
  __shared__ float hid[100];
  if (tid < HIDW) pg[tid] = pooled[g * HIDW + tid];
  __syncthreads();
  if (tid < 100) {
    float a = bc1[tid];
    for (int k = 0; k < HIDW; ++k) a = fmaf(pg[k], Wc1[k * 100 + tid], a);
    hid[tid] = fmaxf(a, 0.f);
  }
  __syncthreads();
  if (tid < 2) {
    float a = bc2[tid];
    for (int k = 0; k < 100; ++k) a = fmaf(hid[k], Wc2[k * 2 + tid], a);
    out[g * 2 + tid] = a;
  }
}

// ---------------- launch ----------------

extern "C" void kernel_launch(void* const* d_in, const int* in_sizes, int n_in,
                              void* d_out, int out_size, void* d_ws, size_t ws_size,
                              hipStream_t stream) {
  const float* x    = (const float*)d_in[0];
  const int*   ei   = (const int*)d_in[1];
  const int*   batch= (const int*)d_in[2];
  const float* W1 = (const float*)d_in[3];  const float* b1 = (const float*)d_in[4];
  const float* W2 = (const float*)d_in[5];  const float* b2 = (const float*)d_in[6];
  const float* W3 = (const float*)d_in[7];  const float* b3 = (const float*)d_in[8];
  const float* Wg = (const float*)d_in[9];  const float* bg = (const float*)d_in[10];
  const float* Wc1= (const float*)d_in[11]; const float* bc1= (const float*)d_in[12];
  const float* Wc2= (const float*)d_in[13]; const float* bc2= (const float*)d_in[14];
  float* out = (float*)d_out;

  const int n = in_sizes[0] / DIN;     // 40000
  const int E = in_sizes[1] / 2;       // 640000
  const int* src = ei;
  const int* dst = ei + E;

  // workspace carve-up (all segments 16B-aligned)
  int* counts   = (int*)d_ws;               // n
  int* fill     = counts + n;               // n
  int* row_ptr  = fill + n;                 // n+4
  int* gs       = row_ptr + (n + 4);        // 68
  float* dinv   = (float*)(gs + 68);        // n
  int* csr_src  = (int*)(dinv + n);         // E
  float* csr_w  = (float*)(csr_src + E);    // E
  float* pooled = csr_w + E;                // 64*200
  float* partial= pooled + NG * HIDW;       // 64*8*200
  _Float16* wt1h = (_Float16*)(partial + NG * POOL_NC * HIDW);  // 224*128
  _Float16* wt1l = wt1h + 224 * 128;
  _Float16* wt2h = wt1l + 224 * 128;
  _Float16* wt2l = wt2h + 224 * KPAD;
  _Float16* wt3h = wt2l + 224 * KPAD;
  _Float16* wt3l = wt3h + 224 * KPAD;
  _Float16* wtgh = wt3l + 224 * KPAD;
  _Float16* wtgl = wtgh + 224 * KPAD;
  _Float16* bufA = wtgl + 224 * KPAD;           // n*224 f16
  _Float16* bufB = bufA + (long)n * KPAD;       // n*224 f16

  hipMemsetAsync(counts, 0, (size_t)2 * n * sizeof(int), stream);  // counts + fill

  // weight prep (independent of graph build)
  wprep_kernel<<<(224 * 128 + 255) / 256, 256, 0, stream>>>(W1, wt1h, wt1l, 128, 128);
  wprep_kernel<<<(224 * KPAD + 255) / 256, 256, 0, stream>>>(W2, wt2h, wt2l, 200, KPAD);
  wprep_kernel<<<(224 * KPAD + 255) / 256, 256, 0, stream>>>(W3, wt3h, wt3l, 200, KPAD);
  wprep_kernel<<<(224 * KPAD + 255) / 256, 256, 0, stream>>>(Wg, wtgh, wtgl, 200, KPAD);

  int eb = (E + 255) / 256;
  int nb = (n + 255) / 256;
  count_kernel<<<eb, 256, 0, stream>>>(dst, counts, E);
  dinv_kernel<<<nb, 256, 0, stream>>>(counts, dinv, n);
  scan_kernel<<<1, 1024, 0, stream>>>(counts, row_ptr, n);
  fill_kernel<<<eb, 256, 0, stream>>>(src, dst, row_ptr, fill, dinv, csr_src, csr_w, E);
  gstart_kernel<<<nb, 256, 0, stream>>>(batch, gs, n);

  int ab = (n + 3) / 4;                 // agg blocks
  int gb = ((n / 32) * 2 + 3) / 4;      // gemm blocks: 2500 waves -> 625

  // layer 1
  aggx_kernel<<<ab, 256, 0, stream>>>(x, row_ptr, csr_src, csr_w, dinv, bufA, n);
  mgemm_kernel<DIN, 1><<<gb, 256, 0, stream>>>(bufA, wt1h, wt1l, b1, bufB, n);
  // layer 2
  aggh_kernel<<<ab, 256, 0, stream>>>(bufB, row_ptr, csr_src, csr_w, dinv, bufA, n);
  mgemm_kernel<KPAD, 1><<<gb, 256, 0, stream>>>(bufA, wt2h, wt2l, b2, bufB, n);
  // layer 3
  aggh_kernel<<<ab, 256, 0, stream>>>(bufB, row_ptr, csr_src, csr_w, dinv, bufA, n);
  mgemm_kernel<KPAD, 1><<<gb, 256, 0, stream>>>(bufA, wt3h, wt3l, b3, bufB, n);  // h3
  // gate + apply: bufA = h3 * sigmoid(h3 @ Wg + bg)
  mgemm_kernel<KPAD, 2><<<gb, 256, 0, stream>>>(bufB, wtgh, wtgl, bg, bufA, n);
  // mean-pool (two-stage deterministic)
  dim3 pgrid(NG, POOL_NC);
  pool_partial_kernel<<<pgrid, 256, 0, stream>>>(bufA, gs, partial);
  pool_final_kernel<<<NG, 256, 0, stream>>>(partial, gs, pooled);
  // classifier
  classifier_kernel<<<NG, 256, 0, stream>>>(pooled, Wc1, bc1, Wc2, bc2, out);
}

// Round 5
// 463.726 us; speedup vs baseline: 2.6616x; 1.1260x over previous
//
#include <hip/hip_runtime.h>

#define NG 64
#define HIDW 200
#define DIN 128
#define KPAD 224
#define POOL_NC 8

typedef _Float16 half4_t __attribute__((ext_vector_type(4)));
typedef _Float16 half8_t __attribute__((ext_vector_type(8)));
typedef float floatx4 __attribute__((ext_vector_type(4)));

// ---------------- degree / CSR build ----------------

__global__ void count_kernel(const int* __restrict__ dst, int* __restrict__ counts, int E) {
  int e = blockIdx.x * 256 + threadIdx.x;
  if (e < E) atomicAdd(&counts[dst[e]], 1);
}

__global__ void dinv_kernel(const int* __restrict__ counts, float* __restrict__ dinv, int n) {
  int i = blockIdx.x * 256 + threadIdx.x;
  if (i < n) dinv[i] = rsqrtf((float)(counts[i] + 1));  // +1 self-loop
}

__global__ __launch_bounds__(1024) void scan_kernel(const int* __restrict__ counts,
                                                    int* __restrict__ row_ptr, int n) {
  __shared__ int ssum[1024];
  int tid = threadIdx.x;
  int per = (n + 1023) / 1024;
  int start = tid * per;
  int end = start + per; if (end > n) end = n;
  int s = 0;
  for (int i = start; i < end; ++i) s += counts[i];
  ssum[tid] = s;
  __syncthreads();
  for (int off = 1; off < 1024; off <<= 1) {
    int v = 0;
    if (tid >= off) v = ssum[tid - off];
    __syncthreads();
    if (tid >= off) ssum[tid] += v;
    __syncthreads();
  }
  int run = ssum[tid] - s;
  for (int i = start; i < end; ++i) { row_ptr[i] = run; run += counts[i]; }
  if (tid == 1023) row_ptr[n] = ssum[1023];
}

__global__ void fill_kernel(const int* __restrict__ src, const int* __restrict__ dst,
                            const int* __restrict__ row_ptr, int* __restrict__ fill,
                            const float* __restrict__ dinv,
                            int* __restrict__ csr_src, float* __restrict__ csr_w, int E) {
  int e = blockIdx.x * 256 + threadIdx.x;
  if (e >= E) return;
  int d = dst[e];
  int pos = row_ptr[d] + atomicAdd(&fill[d], 1);
  int s = src[e];
  csr_src[pos] = s;
  csr_w[pos] = dinv[s];
}

__global__ void gstart_kernel(const int* __restrict__ batch, int* __restrict__ gs, int n) {
  int i = blockIdx.x * 256 + threadIdx.x;
  if (i >= n) return;
  int b = batch[i];
  if (i == 0) {
    for (int g = 0; g <= b; ++g) gs[g] = 0;
  } else {
    int bp = batch[i - 1];
    for (int g = bp + 1; g <= b; ++g) gs[g] = i;
  }
  if (i == n - 1) {
    for (int g = b + 1; g <= NG; ++g) gs[g] = n;
  }
}

// ---------------- weight prep: W[k][200] fp32 -> WT_h/WT_l [224][KP] f16 ----------------

__global__ void wprep_kernel(const float* __restrict__ W, _Float16* __restrict__ WTh,
                             _Float16* __restrict__ WTl, int K, int KP) {
  int idx = blockIdx.x * 256 + threadIdx.x;
  if (idx >= 224 * KP) return;
  int col = idx / KP, k = idx % KP;
  float v = (col < HIDW && k < K) ? W[(long)k * HIDW + col] : 0.f;
  _Float16 h = (_Float16)v;
  WTh[idx] = h;
  WTl[idx] = (_Float16)(v - (float)h);
}

// ---------------- f32 -> f16 convert (x) ----------------

__global__ void cvt_kernel(const float* __restrict__ in, _Float16* __restrict__ out, int n4) {
  int i = blockIdx.x * 256 + threadIdx.x;
  if (i >= n4) return;
  float4 v = ((const float4*)in)[i];
  half4_t r = {(_Float16)v.x, (_Float16)v.y, (_Float16)v.z, (_Float16)v.w};
  ((half4_t*)out)[i] = r;
}

// ---------------- aggregation: out = D^-1/2 (Adj+I) D^-1/2 h  (f16 in/out) -------------
// wave per node; lanes 0..C-1 own half4 chunks. Edge loop unrolled x8 for MLP:
// 8 independent row-gathers in flight per wave (latency-bound fix, R4 post-mortem).

template <int C>
__global__ __launch_bounds__(256) void agg_kernel(const _Float16* __restrict__ h,
                                                  const int* __restrict__ row_ptr,
                                                  const int* __restrict__ csr_src,
                                                  const float* __restrict__ csr_w,
                                                  const float* __restrict__ dinv,
                                                  _Float16* __restrict__ out, int n) {
  int node = blockIdx.x * 4 + (threadIdx.x >> 6);
  int lane = threadIdx.x & 63;
  if (node >= n || lane >= C) return;
  const half4_t* __restrict__ hp = (const half4_t*)h;
  float di = dinv[node];
  int e0 = row_ptr[node], e1 = row_ptr[node + 1];
  half4_t self = hp[(long)node * C + lane];
  float ax = di * (float)self.x, ay = di * (float)self.y;
  float az = di * (float)self.z, aw = di * (float)self.w;

  int e = e0;
  for (; e + 8 <= e1; e += 8) {
    int s0 = csr_src[e + 0], s1 = csr_src[e + 1], s2 = csr_src[e + 2], s3 = csr_src[e + 3];
    int s4 = csr_src[e + 4], s5 = csr_src[e + 5], s6 = csr_src[e + 6], s7 = csr_src[e + 7];
    float w0 = csr_w[e + 0], w1 = csr_w[e + 1], w2 = csr_w[e + 2], w3 = csr_w[e + 3];
    float w4 = csr_w[e + 4], w5 = csr_w[e + 5], w6 = csr_w[e + 6], w7 = csr_w[e + 7];
    half4_t v0 = hp[(long)s0 * C + lane];
    half4_t v1 = hp[(long)s1 * C + lane];
    half4_t v2 = hp[(long)s2 * C + lane];
    half4_t v3 = hp[(long)s3 * C + lane];
    half4_t v4 = hp[(long)s4 * C + lane];
    half4_t v5 = hp[(long)s5 * C + lane];
    half4_t v6 = hp[(long)s6 * C + lane];
    half4_t v7 = hp[(long)s7 * C + lane];
    ax = fmaf(w0, (float)v0.x, ax); ay = fmaf(w0, (float)v0.y, ay);
    az = fmaf(w0, (float)v0.z, az); aw = fmaf(w0, (float)v0.w, aw);
    ax = fmaf(w1, (float)v1.x, ax); ay = fmaf(w1, (float)v1.y, ay);
    az = fmaf(w1, (float)v1.z, az); aw = fmaf(w1, (float)v1.w, aw);
    ax = fmaf(w2, (float)v2.x, ax); ay = fmaf(w2, (float)v2.y, ay);
    az = fmaf(w2, (float)v2.z, az); aw = fmaf(w2, (float)v2.w, aw);
    ax = fmaf(w3, (float)v3.x, ax); ay = fmaf(w3, (float)v3.y, ay);
    az = fmaf(w3, (float)v3.z, az); aw = fmaf(w3, (float)v3.w, aw);
    ax = fmaf(w4, (float)v4.x, ax); ay = fmaf(w4, (float)v4.y, ay);
    az = fmaf(w4, (float)v4.z, az); aw = fmaf(w4, (float)v4.w, aw);
    ax = fmaf(w5, (float)v5.x, ax); ay = fmaf(w5, (float)v5.y, ay);
    az = fmaf(w5, (float)v5.z, az); aw = fmaf(w5, (float)v5.w, aw);
    ax = fmaf(w6, (float)v6.x, ax); ay = fmaf(w6, (float)v6.y, ay);
    az = fmaf(w6, (float)v6.z, az); aw = fmaf(w6, (float)v6.w, aw);
    ax = fmaf(w7, (float)v7.x, ax); ay = fmaf(w7, (float)v7.y, ay);
    az = fmaf(w7, (float)v7.z, az); aw = fmaf(w7, (float)v7.w, aw);
  }
  for (; e < e1; ++e) {
    int s = csr_src[e];
    float w = csr_w[e];
    half4_t v = hp[(long)s * C + lane];
    ax = fmaf(w, (float)v.x, ax); ay = fmaf(w, (float)v.y, ay);
    az = fmaf(w, (float)v.z, az); aw = fmaf(w, (float)v.w, aw);
  }
  half4_t r = {(_Float16)(di * ax), (_Float16)(di * ay),
               (_Float16)(di * az), (_Float16)(di * aw)};
  ((half4_t*)out)[(long)node * C + lane] = r;
}

// ---------------- MFMA GEMM, no LDS, no barriers ----------------
// out[N][224] (f16) = relu/gate(A[N][KP] (f16) @ W + b). Wave tile 32x112.
// __launch_bounds__(256,4): VGPR cap 128 -> 4 waves/SIMD (R4 was 3).
// MODE: 1 = relu, 2 = gated (A[row][col] * sigmoid(acc+bias), A==h3)

template <int KP, int MODE>
__global__ __launch_bounds__(256, 4) void mgemm_kernel(const _Float16* __restrict__ A,
                                                       const _Float16* __restrict__ WTh,
                                                       const _Float16* __restrict__ WTl,
                                                       const float* __restrict__ bias,
                                                       _Float16* __restrict__ out, int N) {
  int tid = threadIdx.x;
  int lane = tid & 63;
  int w = blockIdx.x * 4 + (tid >> 6);
  int wt = w >> 1;
  int wc = w & 1;
  int row0 = wt * 32;
  if (row0 >= N) return;
  int l15 = lane & 15;
  int lq = lane >> 4;

  const _Float16* __restrict__ pa0 = A + (long)(row0 + l15) * KP + lq * 8;
  const _Float16* __restrict__ pa1 = pa0 + 16 * KP;
  const _Float16* __restrict__ pbh = WTh + (long)(wc * 112 + l15) * KP + lq * 8;
  const _Float16* __restrict__ pbl = WTl + (long)(wc * 112 + l15) * KP + lq * 8;

  floatx4 acc[2][7];
#pragma unroll
  for (int i = 0; i < 2; ++i)
#pragma unroll
    for (int j = 0; j < 7; ++j) acc[i][j] = (floatx4){0.f, 0.f, 0.f, 0.f};

#pragma unroll
  for (int k0 = 0; k0 < KP; k0 += 32) {
    half8_t a0 = *(const half8_t*)(pa0 + k0);
    half8_t a1 = *(const half8_t*)(pa1 + k0);
#pragma unroll
    for (int cf = 0; cf < 7; ++cf) {
      half8_t bh = *(const half8_t*)(pbh + (long)cf * 16 * KP + k0);
      acc[0][cf] = __builtin_amdgcn_mfma_f32_16x16x32_f16(a0, bh, acc[0][cf], 0, 0, 0);
      acc[1][cf] = __builtin_amdgcn_mfma_f32_16x16x32_f16(a1, bh, acc[1][cf], 0, 0, 0);
    }
#pragma unroll
    for (int cf = 0; cf < 7; ++cf) {
      half8_t bl = *(const half8_t*)(pbl + (long)cf * 16 * KP + k0);
      acc[0][cf] = __builtin_amdgcn_mfma_f32_16x16x32_f16(a0, bl, acc[0][cf], 0, 0, 0);
      acc[1][cf] = __builtin_amdgcn_mfma_f32_16x16x32_f16(a1, bl, acc[1][cf], 0, 0, 0);
    }
  }

#pragma unroll
  for (int cf = 0; cf < 7; ++cf) {
    int col = wc * 112 + cf * 16 + l15;
    float bs = (col < HIDW) ? bias[col] : 0.f;
#pragma unroll
    for (int rf = 0; rf < 2; ++rf) {
      int rbase = row0 + rf * 16 + lq * 4;
#pragma unroll
      for (int j = 0; j < 4; ++j) {
        int row = rbase + j;
        float v = acc[rf][cf][j] + bs;
        if (MODE == 1) v = fmaxf(v, 0.f);
        if (MODE == 2) {
          float hv = (float)A[(long)row * KP + col];
          v = hv * (1.f / (1.f + __expf(-v)));
        }
        if (col >= HIDW) v = 0.f;  // keep pads zero
        out[(long)row * KPAD + col] = (_Float16)v;
      }
    }
  }
}

// ---------------- mean pool over gated f16 features (two-stage, deterministic) --------

__global__ __launch_bounds__(256) void pool_partial_kernel(const _Float16* __restrict__ gated,
                                                           const int* __restrict__ gs,
                                                           float* __restrict__ partial) {
  int g = blockIdx.x;
  int c = blockIdx.y;
  int f = threadIdx.x;
  int s = gs[g], e = gs[g + 1];
  int len = e - s;
  int chunk = (len + POOL_NC - 1) / POOL_NC;
  int i0 = s + c * chunk;
  int i1 = i0 + chunk; if (i1 > e) i1 = e;
  if (f < HIDW) {
    float acc = 0.f;
    for (int i = i0; i < i1; ++i) acc += (float)gated[(long)i * KPAD + f];
    partial[(g * POOL_NC + c) * HIDW + f] = acc;
  }
}

__global__ __launch_bounds__(256) void pool_final_kernel(const float* __restrict__ partial,
                                                         const int* __restrict__ gs,
                                                         float* __restrict__ pooled) {
  int g = blockIdx.x;
  int f = threadIdx.x;
  if (f >= HIDW) return;
  float acc = 0.f;
#pragma unroll
  for (int c = 0; c < POOL_NC; ++c) acc += partial[(g * POOL_NC + c) * HIDW + f];
  float cnt = fmaxf((float)(gs[g + 1] - gs[g]), 1.f);
  pooled[g * HIDW + f] = acc / cnt;
}

// ---------------- classifier ----------------

__global__ void classifier_kernel(const float* __restrict__ pooled,
                                  const float* __restrict__ Wc1, const float* __restrict__ bc1,
                                  const float* __restrict__ Wc2, const float* __restrict__ bc2,
                                  float* __restrict__ out) {
  int g = blockIdx.x;
  int tid = threadIdx.x;
  __shared__ float pg[HIDW];
  __shared__ float hid[100];
  if (tid < HIDW) pg[tid] = pooled[g * HIDW + tid];
  __syncthreads();
  if (tid < 100) {
    float a = bc1[tid];
    for (int k = 0; k < HIDW; ++k) a = fmaf(pg[k], Wc1[k * 100 + tid], a);
    hid[tid] = fmaxf(a, 0.f);
  }
  __syncthreads();
  if (tid < 2) {
    float a = bc2[tid];
    for (int k = 0; k < 100; ++k) a = fmaf(hid[k], Wc2[k * 2 + tid], a);
    out[g * 2 + tid] = a;
  }
}

// ---------------- launch ----------------

extern "C" void kernel_launch(void* const* d_in, const int* in_sizes, int n_in,
                              void* d_out, int out_size, void* d_ws, size_t ws_size,
                              hipStream_t stream) {
  const float* x    = (const float*)d_in[0];
  const int*   ei   = (const int*)d_in[1];
  const int*   batch= (const int*)d_in[2];
  const float* W1 = (const float*)d_in[3];  const float* b1 = (const float*)d_in[4];
  const float* W2 = (const float*)d_in[5];  const float* b2 = (const float*)d_in[6];
  const float* W3 = (const float*)d_in[7];  const float* b3 = (const float*)d_in[8];
  const float* Wg = (const float*)d_in[9];  const float* bg = (const float*)d_in[10];
  const float* Wc1= (const float*)d_in[11]; const float* bc1= (const float*)d_in[12];
  const float* Wc2= (const float*)d_in[13]; const float* bc2= (const float*)d_in[14];
  float* out = (float*)d_out;

  const int n = in_sizes[0] / DIN;     // 40000
  const int E = in_sizes[1] / 2;       // 640000
  const int* src = ei;
  const int* dst = ei + E;

  // workspace carve-up (all segments 16B-aligned)
  int* counts   = (int*)d_ws;               // n
  int* fill     = counts + n;               // n
  int* row_ptr  = fill + n;                 // n+4
  int* gs       = row_ptr + (n + 4);        // 68
  float* dinv   = (float*)(gs + 68);        // n
  int* csr_src  = (int*)(dinv + n);         // E
  float* csr_w  = (float*)(csr_src + E);    // E
  float* pooled = csr_w + E;                // 64*200
  float* partial= pooled + NG * HIDW;       // 64*8*200
  _Float16* wt1h = (_Float16*)(partial + NG * POOL_NC * HIDW);  // 224*128
  _Float16* wt1l = wt1h + 224 * 128;
  _Float16* wt2h = wt1l + 224 * 128;
  _Float16* wt2l = wt2h + 224 * KPAD;
  _Float16* wt3h = wt2l + 224 * KPAD;
  _Float16* wt3l = wt3h + 224 * KPAD;
  _Float16* wtgh = wt3l + 224 * KPAD;
  _Float16* wtgl = wtgh + 224 * KPAD;
  _Float16* xh   = wtgl + 224 * KPAD;           // n*128 f16
  _Float16* bufA = xh + (long)n * DIN;          // n*224 f16
  _Float16* bufB = bufA + (long)n * KPAD;       // n*224 f16

  hipMemsetAsync(counts, 0, (size_t)2 * n * sizeof(int), stream);  // counts + fill

  // weight prep + x convert (independent of graph build)
  wprep_kernel<<<(224 * 128 + 255) / 256, 256, 0, stream>>>(W1, wt1h, wt1l, 128, 128);
  wprep_kernel<<<(224 * KPAD + 255) / 256, 256, 0, stream>>>(W2, wt2h, wt2l, 200, KPAD);
  wprep_kernel<<<(224 * KPAD + 255) / 256, 256, 0, stream>>>(W3, wt3h, wt3l, 200, KPAD);
  wprep_kernel<<<(224 * KPAD + 255) / 256, 256, 0, stream>>>(Wg, wtgh, wtgl, 200, KPAD);
  cvt_kernel<<<((n * DIN / 4) + 255) / 256, 256, 0, stream>>>(x, xh, n * DIN / 4);

  int eb = (E + 255) / 256;
  int nb = (n + 255) / 256;
  count_kernel<<<eb, 256, 0, stream>>>(dst, counts, E);
  dinv_kernel<<<nb, 256, 0, stream>>>(counts, dinv, n);
  scan_kernel<<<1, 1024, 0, stream>>>(counts, row_ptr, n);
  fill_kernel<<<eb, 256, 0, stream>>>(src, dst, row_ptr, fill, dinv, csr_src, csr_w, E);
  gstart_kernel<<<nb, 256, 0, stream>>>(batch, gs, n);

  int ab = (n + 3) / 4;                 // agg blocks
  int gb = ((n / 32) * 2 + 3) / 4;      // gemm blocks: 2500 waves -> 625

  // layer 1 (width 128 f16)
  agg_kernel<32><<<ab, 256, 0, stream>>>(xh, row_ptr, csr_src, csr_w, dinv, bufA, n);
  mgemm_kernel<DIN, 1><<<gb, 256, 0, stream>>>(bufA, wt1h, wt1l, b1, bufB, n);
  // layer 2
  agg_kernel<56><<<ab, 256, 0, stream>>>(bufB, row_ptr, csr_src, csr_w, dinv, bufA, n);
  mgemm_kernel<KPAD, 1><<<gb, 256, 0, stream>>>(bufA, wt2h, wt2l, b2, bufB, n);
  // layer 3
  agg_kernel<56><<<ab, 256, 0, stream>>>(bufB, row_ptr, csr_src, csr_w, dinv, bufA, n);
  mgemm_kernel<KPAD, 1><<<gb, 256, 0, stream>>>(bufA, wt3h, wt3l, b3, bufB, n);  // h3
  // gate + apply: bufA = h3 * sigmoid(h3 @ Wg + bg)
  mgemm_kernel<KPAD, 2><<<gb, 256, 0, stream>>>(bufB, wtgh, wtgl, bg, bufA, n);
  // mean-pool (two-stage deterministic)
  dim3 pgrid(NG, POOL_NC);
  pool_partial_kernel<<<pgrid, 256, 0, stream>>>(bufA, gs, partial);
  pool_final_kernel<<<NG, 256, 0, stream>>>(partial, gs, pooled);
  // classifier
  classifier_kernel<<<NG, 256, 0, stream>>>(pooled, Wc1, bc1, Wc2, bc2, out);
}

// Round 6
// 401.246 us; speedup vs baseline: 3.0761x; 1.1557x over previous
//
#include <hip/hip_runtime.h>

#define NG 64
#define HIDW 200
#define DIN 128
#define KPAD 224
#define POOL_NC 8

typedef _Float16 half4_t __attribute__((ext_vector_type(4)));
typedef _Float16 half8_t __attribute__((ext_vector_type(8)));
typedef float floatx4 __attribute__((ext_vector_type(4)));

// ---------------- build: degree count + graph-start table (fused) ----------------

__global__ void build_kernel(const int* __restrict__ dst, int* __restrict__ counts,
                             const int* __restrict__ batch, int* __restrict__ gs,
                             int E, int n) {
  int i = blockIdx.x * 256 + threadIdx.x;
  if (i < E) atomicAdd(&counts[dst[i]], 1);
  if (i < n) {
    int b = batch[i];
    if (i == 0) {
      for (int g = 0; g <= b; ++g) gs[g] = 0;
    } else {
      int bp = batch[i - 1];
      for (int g = bp + 1; g <= b; ++g) gs[g] = i;
    }
    if (i == n - 1) {
      for (int g = b + 1; g <= NG; ++g) gs[g] = n;
    }
  }
}

// ---------------- 3-phase parallel exclusive scan (counts -> row_ptr) ----------------
// phase 1: per-block sums (coalesced) + fused dinv = rsqrt(deg+1)

__global__ __launch_bounds__(256) void scan1_kernel(const int* __restrict__ counts,
                                                    int* __restrict__ blocksum,
                                                    float* __restrict__ dinv, int n) {
  __shared__ int s[256];
  int tid = threadIdx.x;
  int i = blockIdx.x * 256 + tid;
  int c = (i < n) ? counts[i] : 0;
  if (i < n) dinv[i] = rsqrtf((float)(c + 1));
  s[tid] = c;
  __syncthreads();
#pragma unroll
  for (int off = 128; off > 0; off >>= 1) {
    if (tid < off) s[tid] += s[tid + off];
    __syncthreads();
  }
  if (tid == 0) blocksum[blockIdx.x] = s[0];
}

// phase 2: exclusive scan of block sums (nb <= 1024), one block

__global__ __launch_bounds__(1024) void scan2_kernel(int* __restrict__ blocksum, int nb) {
  __shared__ int s[1024];
  int tid = threadIdx.x;
  int v = (tid < nb) ? blocksum[tid] : 0;
  s[tid] = v;
  __syncthreads();
  for (int off = 1; off < 1024; off <<= 1) {
    int t = (tid >= off) ? s[tid - off] : 0;
    __syncthreads();
    s[tid] += t;
    __syncthreads();
  }
  if (tid < nb) blocksum[tid] = s[tid] - v;  // exclusive
}

// phase 3: within-block exclusive scan + block offset -> row_ptr

__global__ __launch_bounds__(256) void scan3_kernel(const int* __restrict__ counts,
                                                    const int* __restrict__ blocksum,
                                                    int* __restrict__ row_ptr, int n) {
  __shared__ int s[256];
  int tid = threadIdx.x;
  int i = blockIdx.x * 256 + tid;
  int c = (i < n) ? counts[i] : 0;
  s[tid] = c;
  __syncthreads();
  for (int off = 1; off < 256; off <<= 1) {
    int t = (tid >= off) ? s[tid - off] : 0;
    __syncthreads();
    s[tid] += t;
    __syncthreads();
  }
  int base = blocksum[blockIdx.x];
  if (i < n) row_ptr[i] = base + s[tid] - c;
  if (i == n - 1) row_ptr[n] = base + s[tid];
}

__global__ void fill_kernel(const int* __restrict__ src, const int* __restrict__ dst,
                            const int* __restrict__ row_ptr, int* __restrict__ fill,
                            const float* __restrict__ dinv,
                            int* __restrict__ csr_src, float* __restrict__ csr_w, int E) {
  int e = blockIdx.x * 256 + threadIdx.x;
  if (e >= E) return;
  int d = dst[e];
  int pos = row_ptr[d] + atomicAdd(&fill[d], 1);
  int s = src[e];
  csr_src[pos] = s;
  csr_w[pos] = dinv[s];
}

// ---------------- weight prep: W[k][200] fp32 -> WT_h/WT_l [224][KP] f16 ----------------

__global__ void wprep_kernel(const float* __restrict__ W, _Float16* __restrict__ WTh,
                             _Float16* __restrict__ WTl, int K, int KP) {
  int idx = blockIdx.x * 256 + threadIdx.x;
  if (idx >= 224 * KP) return;
  int col = idx / KP, k = idx % KP;
  float v = (col < HIDW && k < K) ? W[(long)k * HIDW + col] : 0.f;
  _Float16 h = (_Float16)v;
  WTh[idx] = h;
  WTl[idx] = (_Float16)(v - (float)h);
}

// ---------------- f32 -> f16 convert (x) ----------------

__global__ void cvt_kernel(const float* __restrict__ in, _Float16* __restrict__ out, int n4) {
  int i = blockIdx.x * 256 + threadIdx.x;
  if (i >= n4) return;
  float4 v = ((const float4*)in)[i];
  half4_t r = {(_Float16)v.x, (_Float16)v.y, (_Float16)v.z, (_Float16)v.w};
  ((half4_t*)out)[i] = r;
}

// ---------------- aggregation: out = D^-1/2 (Adj+I) D^-1/2 h  (f16 in/out) -------------
// wave per node; lanes 0..C-1 own half4 chunks; edge loop unrolled x8 (MLP)

template <int C>
__global__ __launch_bounds__(256) void agg_kernel(const _Float16* __restrict__ h,
                                                  const int* __restrict__ row_ptr,
                                                  const int* __restrict__ csr_src,
                                                  const float* __restrict__ csr_w,
                                                  const float* __restrict__ dinv,
                                                  _Float16* __restrict__ out, int n) {
  int node = blockIdx.x * 4 + (threadIdx.x >> 6);
  int lane = threadIdx.x & 63;
  if (node >= n || lane >= C) return;
  const half4_t* __restrict__ hp = (const half4_t*)h;
  float di = dinv[node];
  int e0 = row_ptr[node], e1 = row_ptr[node + 1];
  half4_t self = hp[(long)node * C + lane];
  float ax = di * (float)self.x, ay = di * (float)self.y;
  float az = di * (float)self.z, aw = di * (float)self.w;

  int e = e0;
  for (; e + 8 <= e1; e += 8) {
    int s0 = csr_src[e + 0], s1 = csr_src[e + 1], s2 = csr_src[e + 2], s3 = csr_src[e + 3];
    int s4 = csr_src[e + 4], s5 = csr_src[e + 5], s6 = csr_src[e + 6], s7 = csr_src[e + 7];
    float w0 = csr_w[e + 0], w1 = csr_w[e + 1], w2 = csr_w[e + 2], w3 = csr_w[e + 3];
    float w4 = csr_w[e + 4], w5 = csr_w[e + 5], w6 = csr_w[e + 6], w7 = csr_w[e + 7];
    half4_t v0 = hp[(long)s0 * C + lane];
    half4_t v1 = hp[(long)s1 * C + lane];
    half4_t v2 = hp[(long)s2 * C + lane];
    half4_t v3 = hp[(long)s3 * C + lane];
    half4_t v4 = hp[(long)s4 * C + lane];
    half4_t v5 = hp[(long)s5 * C + lane];
    half4_t v6 = hp[(long)s6 * C + lane];
    half4_t v7 = hp[(long)s7 * C + lane];
    ax = fmaf(w0, (float)v0.x, ax); ay = fmaf(w0, (float)v0.y, ay);
    az = fmaf(w0, (float)v0.z, az); aw = fmaf(w0, (float)v0.w, aw);
    ax = fmaf(w1, (float)v1.x, ax); ay = fmaf(w1, (float)v1.y, ay);
    az = fmaf(w1, (float)v1.z, az); aw = fmaf(w1, (float)v1.w, aw);
    ax = fmaf(w2, (float)v2.x, ax); ay = fmaf(w2, (float)v2.y, ay);
    az = fmaf(w2, (float)v2.z, az); aw = fmaf(w2, (float)v2.w, aw);
    ax = fmaf(w3, (float)v3.x, ax); ay = fmaf(w3, (float)v3.y, ay);
    az = fmaf(w3, (float)v3.z, az); aw = fmaf(w3, (float)v3.w, aw);
    ax = fmaf(w4, (float)v4.x, ax); ay = fmaf(w4, (float)v4.y, ay);
    az = fmaf(w4, (float)v4.z, az); aw = fmaf(w4, (float)v4.w, aw);
    ax = fmaf(w5, (float)v5.x, ax); ay = fmaf(w5, (float)v5.y, ay);
    az = fmaf(w5, (float)v5.z, az); aw = fmaf(w5, (float)v5.w, aw);
    ax = fmaf(w6, (float)v6.x, ax); ay = fmaf(w6, (float)v6.y, ay);
    az = fmaf(w6, (float)v6.z, az); aw = fmaf(w6, (float)v6.w, aw);
    ax = fmaf(w7, (float)v7.x, ax); ay = fmaf(w7, (float)v7.y, ay);
    az = fmaf(w7, (float)v7.z, az); aw = fmaf(w7, (float)v7.w, aw);
  }
  for (; e < e1; ++e) {
    int s = csr_src[e];
    float w = csr_w[e];
    half4_t v = hp[(long)s * C + lane];
    ax = fmaf(w, (float)v.x, ax); ay = fmaf(w, (float)v.y, ay);
    az = fmaf(w, (float)v.z, az); aw = fmaf(w, (float)v.w, aw);
  }
  half4_t r = {(_Float16)(di * ax), (_Float16)(di * ay),
               (_Float16)(di * az), (_Float16)(di * aw)};
  ((half4_t*)out)[(long)node * C + lane] = r;
}

// ---------------- MFMA GEMM, no LDS, no barriers ----------------
// out[N][224] (f16) = relu/gate(A[N][KP] (f16) @ W + b). Wave tile 32x112.
// MODE: 1 = relu, 2 = gated (A[row][col] * sigmoid(acc+bias), A==h3)

template <int KP, int MODE>
__global__ __launch_bounds__(256, 4) void mgemm_kernel(const _Float16* __restrict__ A,
                                                       const _Float16* __restrict__ WTh,
                                                       const _Float16* __restrict__ WTl,
                                                       const float* __restrict__ bias,
                                                       _Float16* __restrict__ out, int N) {
  int tid = threadIdx.x;
  int lane = tid & 63;
  int w = blockIdx.x * 4 + (tid >> 6);
  int wt = w >> 1;
  int wc = w & 1;
  int row0 = wt * 32;
  if (row0 >= N) return;
  int l15 = lane & 15;
  int lq = lane >> 4;

  const _Float16* __restrict__ pa0 = A + (long)(row0 + l15) * KP + lq * 8;
  const _Float16* __restrict__ pa1 = pa0 + 16 * KP;
  const _Float16* __restrict__ pbh = WTh + (long)(wc * 112 + l15) * KP + lq * 8;
  const _Float16* __restrict__ pbl = WTl + (long)(wc * 112 + l15) * KP + lq * 8;

  floatx4 acc[2][7];
#pragma unroll
  for (int i = 0; i < 2; ++i)
#pragma unroll
    for (int j = 0; j < 7; ++j) acc[i][j] = (floatx4){0.f, 0.f, 0.f, 0.f};

#pragma unroll
  for (int k0 = 0; k0 < KP; k0 += 32) {
    half8_t a0 = *(const half8_t*)(pa0 + k0);
    half8_t a1 = *(const half8_t*)(pa1 + k0);
#pragma unroll
    for (int cf = 0; cf < 7; ++cf) {
      half8_t bh = *(const half8_t*)(pbh + (long)cf * 16 * KP + k0);
      acc[0][cf] = __builtin_amdgcn_mfma_f32_16x16x32_f16(a0, bh, acc[0][cf], 0, 0, 0);
      acc[1][cf] = __builtin_amdgcn_mfma_f32_16x16x32_f16(a1, bh, acc[1][cf], 0, 0, 0);
    }
#pragma unroll
    for (int cf = 0; cf < 7; ++cf) {
      half8_t bl = *(const half8_t*)(pbl + (long)cf * 16 * KP + k0);
      acc[0][cf] = __builtin_amdgcn_mfma_f32_16x16x32_f16(a0, bl, acc[0][cf], 0, 0, 0);
      acc[1][cf] = __builtin_amdgcn_mfma_f32_16x16x32_f16(a1, bl, acc[1][cf], 0, 0, 0);
    }
  }

#pragma unroll
  for (int cf = 0; cf < 7; ++cf) {
    int col = wc * 112 + cf * 16 + l15;
    float bs = (col < HIDW) ? bias[col] : 0.f;
#pragma unroll
    for (int rf = 0; rf < 2; ++rf) {
      int rbase = row0 + rf * 16 + lq * 4;
#pragma unroll
      for (int j = 0; j < 4; ++j) {
        int row = rbase + j;
        float v = acc[rf][cf][j] + bs;
        if (MODE == 1) v = fmaxf(v, 0.f);
        if (MODE == 2) {
          float hv = (float)A[(long)row * KP + col];
          v = hv * (1.f / (1.f + __expf(-v)));
        }
        if (col >= HIDW) v = 0.f;  // keep pads zero
        out[(long)row * KPAD + col] = (_Float16)v;
      }
    }
  }
}

// ---------------- mean pool partials over gated f16 features ----------------

__global__ __launch_bounds__(256) void pool_partial_kernel(const _Float16* __restrict__ gated,
                                                           const int* __restrict__ gs,
                                                           float* __restrict__ partial) {
  int g = blockIdx.x;
  int c = blockIdx.y;
  int f = threadIdx.x;
  int s = gs[g], e = gs[g + 1];
  int len = e - s;
  int chunk = (len + POOL_NC - 1) / POOL_NC;
  int i0 = s + c * chunk;
  int i1 = i0 + chunk; if (i1 > e) i1 = e;
  if (f < HIDW) {
    float acc = 0.f;
    for (int i = i0; i < i1; ++i) acc += (float)gated[(long)i * KPAD + f];
    partial[(g * POOL_NC + c) * HIDW + f] = acc;
  }
}

// ---------------- classifier (fused pool-final): partial -> logits ----------------

__global__ void classifier_kernel(const float* __restrict__ partial,
                                  const int* __restrict__ gs,
                                  const float* __restrict__ Wc1, const float* __restrict__ bc1,
                                  const float* __restrict__ Wc2, const float* __restrict__ bc2,
                                  float* __restrict__ out) {
  int g = blockIdx.x;
  int tid = threadIdx.x;
  __shared__ float pg[HIDW];
  __shared__ float hid[100];
  if (tid < HIDW) {
    float acc = 0.f;
#pragma unroll
    for (int c = 0; c < POOL_NC; ++c) acc += partial[(g * POOL_NC + c) * HIDW + tid];
    float cnt = fmaxf((float)(gs[g + 1] - gs[g]), 1.f);
    pg[tid] = acc / cnt;
  }
  __syncthreads();
  if (tid < 100) {
    float a = bc1[tid];
    for (int k = 0; k < HIDW; ++k) a = fmaf(pg[k], Wc1[k * 100 + tid], a);
    hid[tid] = fmaxf(a, 0.f);
  }
  __syncthreads();
  if (tid < 2) {
    float a = bc2[tid];
    for (int k = 0; k < 100; ++k) a = fmaf(hid[k], Wc2[k * 2 + tid], a);
    out[g * 2 + tid] = a;
  }
}

// ---------------- launch ----------------

extern "C" void kernel_launch(void* const* d_in, const int* in_sizes, int n_in,
                              void* d_out, int out_size, void* d_ws, size_t ws_size,
                              hipStream_t stream) {
  const float* x    = (const float*)d_in[0];
  const int*   ei   = (const int*)d_in[1];
  const int*   batch= (const int*)d_in[2];
  const float* W1 = (const float*)d_in[3];  const float* b1 = (const float*)d_in[4];
  const float* W2 = (const float*)d_in[5];  const float* b2 = (const float*)d_in[6];
  const float* W3 = (const float*)d_in[7];  const float* b3 = (const float*)d_in[8];
  const float* Wg = (const float*)d_in[9];  const float* bg = (const float*)d_in[10];
  const float* Wc1= (const float*)d_in[11]; const float* bc1= (const float*)d_in[12];
  const float* Wc2= (const float*)d_in[13]; const float* bc2= (const float*)d_in[14];
  float* out = (float*)d_out;

  const int n = in_sizes[0] / DIN;     // 40000
  const int E = in_sizes[1] / 2;       // 640000
  const int* src = ei;
  const int* dst = ei + E;
  const int nb256 = (n + 255) / 256;   // 157 scan blocks

  // workspace carve-up (all segments 16B-aligned)
  int* counts   = (int*)d_ws;               // n
  int* fill     = counts + n;               // n
  int* row_ptr  = fill + n;                 // n+4
  int* gs       = row_ptr + (n + 4);        // 68
  int* blocksum = gs + 68;                  // 1024 (pad)
  float* dinv   = (float*)(blocksum + 1024);// n
  int* csr_src  = (int*)(dinv + n);         // E
  float* csr_w  = (float*)(csr_src + E);    // E
  float* partial= csr_w + E;                // 64*8*200
  _Float16* wt1h = (_Float16*)(partial + NG * POOL_NC * HIDW);  // 224*128
  _Float16* wt1l = wt1h + 224 * 128;
  _Float16* wt2h = wt1l + 224 * 128;
  _Float16* wt2l = wt2h + 224 * KPAD;
  _Float16* wt3h = wt2l + 224 * KPAD;
  _Float16* wt3l = wt3h + 224 * KPAD;
  _Float16* wtgh = wt3l + 224 * KPAD;
  _Float16* wtgl = wtgh + 224 * KPAD;
  _Float16* xh   = wtgl + 224 * KPAD;           // n*128 f16
  _Float16* bufA = xh + (long)n * DIN;          // n*224 f16
  _Float16* bufB = bufA + (long)n * KPAD;       // n*224 f16

  hipMemsetAsync(counts, 0, (size_t)2 * n * sizeof(int), stream);  // counts + fill

  // weight prep + x convert (independent of graph build)
  wprep_kernel<<<(224 * 128 + 255) / 256, 256, 0, stream>>>(W1, wt1h, wt1l, 128, 128);
  wprep_kernel<<<(224 * KPAD + 255) / 256, 256, 0, stream>>>(W2, wt2h, wt2l, 200, KPAD);
  wprep_kernel<<<(224 * KPAD + 255) / 256, 256, 0, stream>>>(W3, wt3h, wt3l, 200, KPAD);
  wprep_kernel<<<(224 * KPAD + 255) / 256, 256, 0, stream>>>(Wg, wtgh, wtgl, 200, KPAD);
  cvt_kernel<<<((n * DIN / 4) + 255) / 256, 256, 0, stream>>>(x, xh, n * DIN / 4);

  int eb = (E + 255) / 256;
  build_kernel<<<eb, 256, 0, stream>>>(dst, counts, batch, gs, E, n);
  scan1_kernel<<<nb256, 256, 0, stream>>>(counts, blocksum, dinv, n);
  scan2_kernel<<<1, 1024, 0, stream>>>(blocksum, nb256);
  scan3_kernel<<<nb256, 256, 0, stream>>>(counts, blocksum, row_ptr, n);
  fill_kernel<<<eb, 256, 0, stream>>>(src, dst, row_ptr, fill, dinv, csr_src, csr_w, E);

  int ab = (n + 3) / 4;                 // agg blocks
  int gb = ((n / 32) * 2 + 3) / 4;      // gemm blocks: 2500 waves -> 625

  // layer 1 (width 128 f16)
  agg_kernel<32><<<ab, 256, 0, stream>>>(xh, row_ptr, csr_src, csr_w, dinv, bufA, n);
  mgemm_kernel<DIN, 1><<<gb, 256, 0, stream>>>(bufA, wt1h, wt1l, b1, bufB, n);
  // layer 2
  agg_kernel<56><<<ab, 256, 0, stream>>>(bufB, row_ptr, csr_src, csr_w, dinv, bufA, n);
  mgemm_kernel<KPAD, 1><<<gb, 256, 0, stream>>>(bufA, wt2h, wt2l, b2, bufB, n);
  // layer 3
  agg_kernel<56><<<ab, 256, 0, stream>>>(bufB, row_ptr, csr_src, csr_w, dinv, bufA, n);
  mgemm_kernel<KPAD, 1><<<gb, 256, 0, stream>>>(bufA, wt3h, wt3l, b3, bufB, n);  // h3
  // gate + apply: bufA = h3 * sigmoid(h3 @ Wg + bg)
  mgemm_kernel<KPAD, 2><<<gb, 256, 0, stream>>>(bufB, wtgh, wtgl, bg, bufA, n);
  // mean-pool partials + fused pool-final/classifier
  dim3 pgrid(NG, POOL_NC);
  pool_partial_kernel<<<pgrid, 256, 0, stream>>>(bufA, gs, partial);
  classifier_kernel<<<NG, 256, 0, stream>>>(partial, gs, Wc1, bc1, Wc2, bc2, out);
}